// Round 3
// baseline (735.496 us; speedup 1.0000x reference)
//
#include <hip/hip_runtime.h>
#include <hip/hip_fp16.h>

// Problem constants (from reference)
#define Nn 200000
#define Ee 6400000
#define EP 6600000            // Ee + Nn self loops
#define Hh 9
#define Ll 4
#define Gg 2000
#define Cc 2
#define JK 36                 // Ll * Hh
#define NCB ((Nn + 1023) >> 10) // 196 coarse buckets (1024 nodes each)
#define EPB 8192              // edges per phase-A block
#define NBLKA ((EP + EPB - 1) / EPB) // 806
#define NB ((Nn + 255) / 256) // 782
#define NPB 32                // nodes per k_node_agg block (oct per node)
#define NAB (Nn / NPB)        // 6250 blocks
#define CAP 3072              // staged csr entries per block (12 KB)
#define CAPB 36864            // kB_csr staged entries (144 KB; mean 33792 + 17 sigma)
#define HTS (NCB + 1)         // histT row stride

union H2F { __half2 h; float f; };

// ========= CSR build: block-major multisplit + per-bucket LDS sort =========

// Phase A: per-block LDS multisplit, drained BLOCK-MAJOR. Also accumulates
// per-node degrees via fire-and-forget global atomics (R2: feeds the global
// scan that lets kB_csr skip its histogram pass entirely).
// Payload: src (18b) | dst low 10 bits << 18.
__global__ __launch_bounds__(256) void kA_scatter(
    const int* __restrict__ src, const int* __restrict__ dst,
    int* __restrict__ deg, int* __restrict__ histT,
    unsigned* __restrict__ bucketed)
{
    __shared__ unsigned pbuf[EPB];        // 32 KB
    __shared__ int lh[NCB];
    __shared__ int s[256];
    int t = threadIdx.x;
    if (t < NCB) lh[t] = 0;
    __syncthreads();
    const int base = blockIdx.x * EPB;
    const int nseg = min(EPB, EP - base);
    // pass 1: coarse histogram + per-node degree (no-return atomic: no stall)
    for (int j = t; j < nseg; j += 256) {
        int e = base + j;
        int d = (e < Ee) ? dst[e] : (e - Ee);
        atomicAdd(&lh[d >> 10], 1);
        atomicAdd(&deg[d], 1);
    }
    __syncthreads();
    // exclusive scan of 196 bins
    int v = (t < NCB) ? lh[t] : 0;
    s[t] = v; __syncthreads();
    for (int off = 1; off < 256; off <<= 1) {
        int u = (t >= off) ? s[t - off] : 0;
        __syncthreads();
        s[t] += u;
        __syncthreads();
    }
    int* hrow = histT + (size_t)blockIdx.x * HTS;
    if (t < NCB) {
        int ex = s[t] - v;
        lh[t] = ex;                        // LDS cursor
        hrow[t] = ex;                      // run starts for kB
    }
    if (t == 0) hrow[NCB] = nseg;
    __syncthreads();
    // pass 2: scatter into LDS (bucket-ordered within block)
    for (int j = t; j < nseg; j += 256) {
        int e = base + j;
        int sv, d;
        if (e < Ee) { sv = src[e]; d = dst[e]; } else { sv = e - Ee; d = sv; }
        int pos = atomicAdd(&lh[d >> 10], 1);
        pbuf[pos] = (unsigned)sv | ((unsigned)(d & 1023) << 18);
    }
    __syncthreads();
    // pass 3: straight coalesced drain, block-major
    for (int j = t; j < nseg; j += 256)
        bucketed[base + j] = pbuf[j];
}

// Per-bucket exclusive scan of degrees: row_ptr[node] = bucket-RELATIVE
// exclusive prefix; ctot[k] = bucket total. (196 blocks x 1024 threads)
__global__ __launch_bounds__(1024) void k_scan_part(
    const int* __restrict__ deg, int* __restrict__ row_ptr,
    int* __restrict__ ctot)
{
    __shared__ int bh[1024];
    const int k = blockIdx.x;
    const int t = threadIdx.x;
    const int node = (k << 10) + t;
    int v = (node < Nn) ? deg[node] : 0;
    bh[t] = v; __syncthreads();
    for (int off = 1; off < 1024; off <<= 1) {
        int u = (t >= off) ? bh[t - off] : 0;
        __syncthreads();
        bh[t] += u;
        __syncthreads();
    }
    if (node < Nn) row_ptr[node] = bh[t] - v;   // relative; kB absolutizes
    if (t == 1023) ctot[k] = bh[1023];
}

// Scan coarse totals -> cbase.
__global__ __launch_bounds__(256) void k_scan(
    const int* __restrict__ ctot, int* __restrict__ cbase,
    int* __restrict__ row_ptr)
{
    __shared__ int s[256];
    int t = threadIdx.x;
    int v = (t < NCB) ? ctot[t] : 0;
    s[t] = v; __syncthreads();
    for (int off = 1; off < 256; off <<= 1) {
        int u = (t >= off) ? s[t - off] : 0;
        __syncthreads();
        s[t] += u;
        __syncthreads();
    }
    if (t < NCB) cbase[t] = s[t] - v;
    if (t == 0) { cbase[NCB] = EP; row_ptr[Nn] = EP; }
}

// Phase B (R2: scatter-only, latency-optimized). Cursors come from the
// precomputed degree scan (no histogram pass, no 1024-deep block scan).
// Run bounds preloaded to LDS (kills dependent scalar loads per run);
// 4-way run pipelining gives 4 outstanding gathers per wave.
__global__ __launch_bounds__(1024) void kB_csr(
    const unsigned* __restrict__ bucketed, const int* __restrict__ histT,
    const int* __restrict__ cbase, int* __restrict__ row_ptr,
    int* __restrict__ csr_src)
{
    __shared__ int2 hb[NBLKA];            // 6.4 KB run bounds
    __shared__ int cur[1024];
    __shared__ unsigned pbuf[CAPB];       // 144 KB (154 KB total; grid 196 -> 1 blk/CU anyway)
    const int k = blockIdx.x;
    const int t = threadIdx.x;
    const int w = t >> 6, lane = t & 63;  // 16 waves
    // preload run bounds for this bucket (column k of histT)
    for (int j = t; j < NBLKA; j += 1024) {
        const int* hrow = histT + (size_t)j * HTS + k;
        hb[j] = make_int2(hrow[0], hrow[1]);
    }
    const int base_k = cbase[k];
    const int nseg_b = cbase[k + 1] - base_k;
    const bool fit = (nseg_b <= CAPB);
    const int node = (k << 10) + t;
    if (node < Nn) {
        int rel = row_ptr[node];
        row_ptr[node] = base_k + rel;     // absolutize for k_node_agg
        cur[t] = rel;
    } else {
        cur[t] = 0;
    }
    __syncthreads();
    if (fit) {
        // scatter into LDS pbuf, 4 runs in flight per wave
        for (int b = w; b < NBLKA; b += 16 * 4) {
            int2 es[4]; unsigned ps[4];
#pragma unroll
            for (int u = 0; u < 4; ++u) {
                int bb = b + 16 * u;
                int2 e = (bb < NBLKA) ? hb[bb] : make_int2(0, 0);
                es[u] = e;
                int j = e.x + lane;
                ps[u] = (j < e.y)
                    ? __builtin_nontemporal_load(bucketed + (size_t)bb * EPB + j)
                    : 0u;
            }
#pragma unroll
            for (int u = 0; u < 4; ++u) {
                int bb = b + 16 * u;
                if (bb >= NBLKA) break;
                int j = es[u].x + lane;
                if (j < es[u].y) {
                    unsigned p = ps[u];
                    int pos = atomicAdd(&cur[(p >> 18) & 1023], 1);
                    pbuf[pos] = p & 0x3FFFFu;
                }
                for (j += 64; j < es[u].y; j += 64) {   // rare (run > 64)
                    unsigned p = __builtin_nontemporal_load(
                        bucketed + (size_t)bb * EPB + j);
                    int pos = atomicAdd(&cur[(p >> 18) & 1023], 1);
                    pbuf[pos] = p & 0x3FFFFu;
                }
            }
        }
        __syncthreads();
        // fully-coalesced drain
        for (int j = t; j < nseg_b; j += 1024)
            csr_src[base_k + j] = (int)pbuf[j];
    } else {
        // fallback: direct global scatter (correct, slower; statistically never)
        for (int b = w; b < NBLKA; b += 16) {
            int2 e = hb[b];
            int rb = b * EPB;
            for (int j = e.x + lane; j < e.y; j += 64) {
                unsigned p = bucketed[rb + j];
                int pos = base_k + atomicAdd(&cur[(p >> 18) & 1023], 1);
                csr_src[pos] = (int)(p & 0x3FFFFu);
            }
        }
    }
}

// ============ per-layer kernels ============

// Gather-table layout (L2-resident: 3.6 MB total < 4 MB per-XCD L2):
//   A[i]  : 16 B  = h0..h7 as 4x half2              (3.2 MB)
//   Bh[i] :  2 B  = h8 as half                      (0.4 MB)
//   D[i]  :  4 B  = alpha_d fp32 (read per NODE)    (0.8 MB)
// alpha_s is NOT stored: recomputed per edge from the gathered fp16 h.
__global__ __launch_bounds__(256) void k_transform(
    const float* __restrict__ xin, int xstride,
    const float* __restrict__ Wl,
    const float* __restrict__ adst,
    float4* __restrict__ A, __half* __restrict__ Bh, float* __restrict__ D)
{
    int i = blockIdx.x * blockDim.x + threadIdx.x;
    if (i >= Nn) return;
    const float* xp = xin + (size_t)i * xstride;
    float xi[Hh];
#pragma unroll
    for (int k = 0; k < Hh; ++k) xi[k] = xp[k];
    float hv[Hh];
#pragma unroll
    for (int j = 0; j < Hh; ++j) {
        float s = 0.f;
#pragma unroll
        for (int k = 0; k < Hh; ++k) s += xi[k] * Wl[k * Hh + j];
        hv[j] = s;
    }
    float ad = 0.f;
#pragma unroll
    for (int j = 0; j < Hh; ++j) ad += hv[j] * adst[j];
    H2F u01, u23, u45, u67;
    u01.h = __floats2half2_rn(hv[0], hv[1]);
    u23.h = __floats2half2_rn(hv[2], hv[3]);
    u45.h = __floats2half2_rn(hv[4], hv[5]);
    u67.h = __floats2half2_rn(hv[6], hv[7]);
    A[i] = make_float4(u01.f, u23.f, u45.f, u67.f);
    Bh[i] = __float2half(hv[8]);
    D[i] = ad;
}

// Oct-per-node gather with LDS-staged CSR, 2-deep software-pipelined gathers.
// Single-pass softmax: |logits| << 88 so exp never overflows; ratio exact.
__global__ __launch_bounds__(256) void k_node_agg(
    const int* __restrict__ rp, const int* __restrict__ csr,
    const float4* __restrict__ A, const __half* __restrict__ Bh,
    const float* __restrict__ D, const float* __restrict__ asrc,
    const float* __restrict__ biasl,
    float* __restrict__ jk, int l)
{
    __shared__ int scsr[CAP];
    __shared__ int srp[NPB + 1];
    const int nbase = blockIdx.x * NPB;
    const int t = threadIdx.x;
    if (t <= NPB) srp[t] = rp[nbase + t];   // nbase+NPB <= Nn; rp[Nn] = EP
    __syncthreads();
    const int beg_blk = srp[0];
    const int nseg = srp[NPB] - beg_blk;
    const bool use_lds = (nseg <= CAP);
    if (use_lds)
        for (int j = t; j < nseg; j += 256)
            scsr[j] = __builtin_nontemporal_load(csr + beg_blk + j); // streamed
    __syncthreads();

    // att_src for this layer (uniform -> SGPRs)
    const float s0 = asrc[0], s1 = asrc[1], s2 = asrc[2], s3 = asrc[3],
                s4 = asrc[4], s5 = asrc[5], s6 = asrc[6], s7 = asrc[7],
                s8 = asrc[8];

    const int ni = t >> 3;          // node within block
    const int q  = t & 7;           // lane within oct
    const int i  = nbase + ni;
    const float c = D[i];           // own alpha_d (fp32, once per node)
    float a0=0,a1=0,a2=0,a3=0,a4=0,a5=0,a6=0,a7=0,a8=0,den=0;
    if (use_lds) {
        int idx = srp[ni] - beg_blk + q;
        const int iend = srp[ni + 1] - beg_blk;
        int s = (idx < iend) ? scsr[idx] : 0;
        float4 F = A[s];                    // prime the pipeline (s=0 is valid)
        __half hb = Bh[s];
        while (idx < iend) {
            int nidx = idx + 8;
            int sn = (nidx < iend) ? scsr[nidx] : 0;
            float4 Fn = A[sn];              // issue next gather BEFORE using F
            __half hbn = Bh[sn];
            H2F u; float2 p;
            u.f = F.x; p = __half22float2(u.h); float x0 = p.x, x1 = p.y;
            u.f = F.y; p = __half22float2(u.h); float x2 = p.x, x3 = p.y;
            u.f = F.z; p = __half22float2(u.h); float x4 = p.x, x5 = p.y;
            u.f = F.w; p = __half22float2(u.h); float x6 = p.x, x7 = p.y;
            float x8 = __half2float(hb);
            float as = x0*s0 + x1*s1 + x2*s2 + x3*s3 + x4*s4
                     + x5*s5 + x6*s6 + x7*s7 + x8*s8;
            float lg = as + c;
            lg = lg > 0.f ? lg : 0.2f * lg;            // leaky_relu(0.2)
            float w = __expf(lg);
            a0 += w*x0; a1 += w*x1; a2 += w*x2; a3 += w*x3; a4 += w*x4;
            a5 += w*x5; a6 += w*x6; a7 += w*x7; a8 += w*x8;
            den += w;
            F = Fn; hb = hbn; idx = nidx;
        }
    } else {
        for (int e = srp[ni] + q; e < srp[ni + 1]; e += 8) {
            int s = csr[e];
            float4 F = A[s];
            __half hb = Bh[s];
            H2F u; float2 p;
            u.f = F.x; p = __half22float2(u.h); float x0 = p.x, x1 = p.y;
            u.f = F.y; p = __half22float2(u.h); float x2 = p.x, x3 = p.y;
            u.f = F.z; p = __half22float2(u.h); float x4 = p.x, x5 = p.y;
            u.f = F.w; p = __half22float2(u.h); float x6 = p.x, x7 = p.y;
            float x8 = __half2float(hb);
            float as = x0*s0 + x1*s1 + x2*s2 + x3*s3 + x4*s4
                     + x5*s5 + x6*s6 + x7*s7 + x8*s8;
            float lg = as + c;
            lg = lg > 0.f ? lg : 0.2f * lg;
            float w = __expf(lg);
            a0 += w*x0; a1 += w*x1; a2 += w*x2; a3 += w*x3; a4 += w*x4;
            a5 += w*x5; a6 += w*x6; a7 += w*x7; a8 += w*x8;
            den += w;
        }
    }
#pragma unroll
    for (int m = 1; m <= 4; m <<= 1) {
        a0 += __shfl_xor(a0, m); a1 += __shfl_xor(a1, m);
        a2 += __shfl_xor(a2, m); a3 += __shfl_xor(a3, m);
        a4 += __shfl_xor(a4, m); a5 += __shfl_xor(a5, m);
        a6 += __shfl_xor(a6, m); a7 += __shfl_xor(a7, m);
        a8 += __shfl_xor(a8, m); den += __shfl_xor(den, m);
    }
    if (q == 0) {
        float inv = 1.f / den;          // den >= 1 (self-loop term)
        float* jp = jk + (size_t)i * JK + l * Hh;
        float o;
        o = fmaxf(a0*inv + biasl[0], 0.f); __builtin_nontemporal_store(o, jp + 0);
        o = fmaxf(a1*inv + biasl[1], 0.f); __builtin_nontemporal_store(o, jp + 1);
        o = fmaxf(a2*inv + biasl[2], 0.f); __builtin_nontemporal_store(o, jp + 2);
        o = fmaxf(a3*inv + biasl[3], 0.f); __builtin_nontemporal_store(o, jp + 3);
        o = fmaxf(a4*inv + biasl[4], 0.f); __builtin_nontemporal_store(o, jp + 4);
        o = fmaxf(a5*inv + biasl[5], 0.f); __builtin_nontemporal_store(o, jp + 5);
        o = fmaxf(a6*inv + biasl[6], 0.f); __builtin_nontemporal_store(o, jp + 6);
        o = fmaxf(a7*inv + biasl[7], 0.f); __builtin_nontemporal_store(o, jp + 7);
        o = fmaxf(a8*inv + biasl[8], 0.f); __builtin_nontemporal_store(o, jp + 8);
    }
}

// ============ pool + fc ============

// batch is sorted -> graphs are contiguous node ranges. Build range starts.
__global__ __launch_bounds__(256) void k_graph_ptr(
    const int* __restrict__ batch, int* __restrict__ gp)
{
    int i = blockIdx.x * 256 + threadIdx.x;
    if (i >= Nn) return;
    int b = batch[i];
    if (i == 0) {
        for (int g = 0; g <= b; ++g) gp[g] = 0;
    } else {
        int pb = batch[i - 1];
        for (int g = pb + 1; g <= b; ++g) gp[g] = i;
    }
    if (i == Nn - 1) {
        for (int g = b + 1; g <= Gg; ++g) gp[g] = Nn;
    }
}

// Segmented max, one thread per (graph, col). Post-relu values >= 0 and
// init 0 reproduces the isfinite->0 guard for empty graphs.
__global__ __launch_bounds__(256) void k_pool_seg(
    const float* __restrict__ jk, const int* __restrict__ gp,
    float* __restrict__ pooled)
{
    int t = blockIdx.x * 256 + threadIdx.x;
    if (t >= Gg * JK) return;
    int g = t / JK, col = t - g * JK;
    int beg = gp[g], end = gp[g + 1];
    float m = 0.f;
    for (int i = beg; i < end; ++i)
        m = fmaxf(m, jk[(size_t)i * JK + col]);
    pooled[t] = m;
}

__global__ __launch_bounds__(256) void k_fc(
    const float* __restrict__ pooled, const float* __restrict__ fcw,
    const float* __restrict__ fcb, float* __restrict__ out)
{
    int t = blockIdx.x * blockDim.x + threadIdx.x;
    if (t >= Gg * Cc) return;
    int g = t / Cc, c = t - g * Cc;
    float s = fcb[c];
    const float* pp = pooled + (size_t)g * JK;
#pragma unroll
    for (int j = 0; j < JK; ++j) s += pp[j] * fcw[j * Cc + c];
    out[t] = s;
}

extern "C" void kernel_launch(void* const* d_in, const int* in_sizes, int n_in,
                              void* d_out, int out_size, void* d_ws, size_t ws_size,
                              hipStream_t stream) {
    const float* x      = (const float*)d_in[0];   // [N,9]
    const int*   ei     = (const int*)d_in[1];     // [2,E]: src row then dst row
    const int*   batch  = (const int*)d_in[2];     // [N] sorted
    const float* W      = (const float*)d_in[3];   // [L,9,9]
    const float* a_src  = (const float*)d_in[4];   // [L,9]
    const float* a_dst  = (const float*)d_in[5];   // [L,9]
    const float* bias   = (const float*)d_in[6];   // [L,9]
    const float* fc_w   = (const float*)d_in[7];   // [36,2]
    const float* fc_b   = (const float*)d_in[8];   // [2]
    float* out = (float*)d_out;

    // Workspace layout (~61 MB live). histT and deg both alias the A region
    // (first 3.2 MB) — dead before A is first written. bucketed aliases jk.
    float* ws        = (float*)d_ws;
    float4* A        = (float4*)ws;                       // Nn*16B (3.2MB)
    __half* Bh       = (__half*)(ws + (size_t)Nn * 4);    // Nn*2B  (0.4MB)
    float* D         = (float*)((char*)Bh + (size_t)Nn * sizeof(__half)); // Nn*4B
    float* jk        = D + Nn;                            // Nn*JK (28.8MB)
    float* pooled    = jk + (size_t)Nn * JK;              // Gg*JK
    int* row_ptr     = (int*)(pooled + (size_t)Gg * JK);  // Nn+1
    int* gp          = row_ptr + Nn + 1;                  // Gg+1
    int* ctot        = gp + Gg + 1;                       // NCB
    int* cbase       = ctot + NCB;                        // NCB+1
    int* csr_src     = cbase + NCB + 1;                   // EP (26.4MB)
    int* histT       = (int*)ws;                          // aliases A, 635 KB
    int* deg         = (int*)((char*)ws + (1 << 20));     // aliases A @ +1MB, 800 KB
    unsigned* bucketed = (unsigned*)jk;                   // EP alias (26.4MB)

    const int* srcp = ei;
    const int* dstp = ei + Ee;

    // CSR build (edge structure is layer-invariant)
    hipMemsetAsync(deg, 0, Nn * sizeof(int), stream);
    kA_scatter <<<NBLKA, 256, 0, stream>>>(srcp, dstp, deg, histT, bucketed);
    k_scan_part<<<NCB, 1024, 0, stream>>>(deg, row_ptr, ctot);
    k_scan     <<<1, 256, 0, stream>>>(ctot, cbase, row_ptr);
    kB_csr     <<<NCB, 1024, 0, stream>>>(bucketed, histT, cbase, row_ptr, csr_src);

    for (int l = 0; l < Ll; ++l) {
        const float* xin = (l == 0) ? x : (jk + (size_t)(l - 1) * Hh);
        int xstride      = (l == 0) ? Hh : JK;
        k_transform<<<NB, 256, 0, stream>>>(xin, xstride, W + l * Hh * Hh,
                                            a_dst + l * Hh, A, Bh, D);
        k_node_agg<<<NAB, 256, 0, stream>>>(row_ptr, csr_src, A, Bh, D,
                                            a_src + l * Hh, bias + l * Hh, jk, l);
    }
    k_graph_ptr<<<NB, 256, 0, stream>>>(batch, gp);
    k_pool_seg<<<(Gg * JK + 255) / 256, 256, 0, stream>>>(jk, gp, pooled);
    k_fc<<<(Gg * Cc + 255) / 256, 256, 0, stream>>>(pooled, fc_w, fc_b, out);
}

// Round 4
// 556.015 us; speedup vs baseline: 1.3228x; 1.3228x over previous
//
#include <hip/hip_runtime.h>
#include <hip/hip_fp16.h>

// Problem constants (from reference)
#define Nn 200000
#define Ee 6400000
#define EP 6600000            // Ee + Nn self loops
#define Hh 9
#define Ll 4
#define Gg 2000
#define Cc 2
#define JK 36                 // Ll * Hh
#define NCB ((Nn + 1023) >> 10) // 196 coarse buckets (1024 nodes each)
#define EPB 8192              // edges per phase-A block
#define NBLKA ((EP + EPB - 1) / EPB) // 806
#define NB ((Nn + 255) / 256) // 782
#define NPB 32                // nodes per k_node_agg block (oct per node)
#define NAB (Nn / NPB)        // 6250 blocks
#define CAP 3072              // staged csr entries per block (12 KB)
#define CAPB 36864            // kB_csr staged entries (144 KB; mean 33792 + 17 sigma)
#define HTS (NCB + 1)         // histT row stride

union H2F { __half2 h; float f; };

// ========= CSR build: block-major multisplit + per-bucket LDS sort =========

// Phase A: per-block LDS multisplit, drained BLOCK-MAJOR (straight coalesced
// copy). Per-block bucket offsets -> histT row; global bucket totals -> ctot
// (196 LDS-aggregated atomics/block — NOT per-edge; R3 lesson: per-edge
// global atomics cost ~30B HBM each).
// Payload: src (18b) | dst low 10 bits << 18.
__global__ __launch_bounds__(256) void kA_scatter(
    const int* __restrict__ src, const int* __restrict__ dst,
    int* __restrict__ ctot, int* __restrict__ histT,
    unsigned* __restrict__ bucketed)
{
    __shared__ unsigned pbuf[EPB];        // 32 KB
    __shared__ int lh[NCB];
    __shared__ int s[256];
    int t = threadIdx.x;
    if (t < NCB) lh[t] = 0;
    __syncthreads();
    const int base = blockIdx.x * EPB;
    const int nseg = min(EPB, EP - base);
    // pass 1: coarse histogram (dst only)
    for (int j = t; j < nseg; j += 256) {
        int e = base + j;
        int d = (e < Ee) ? dst[e] : (e - Ee);
        atomicAdd(&lh[d >> 10], 1);
    }
    __syncthreads();
    // exclusive scan of 196 bins
    int v = (t < NCB) ? lh[t] : 0;
    s[t] = v; __syncthreads();
    for (int off = 1; off < 256; off <<= 1) {
        int u = (t >= off) ? s[t - off] : 0;
        __syncthreads();
        s[t] += u;
        __syncthreads();
    }
    int* hrow = histT + (size_t)blockIdx.x * HTS;
    if (t < NCB) {
        int ex = s[t] - v;
        lh[t] = ex;                        // LDS cursor
        hrow[t] = ex;                      // run starts for kB
        if (v) atomicAdd(&ctot[t], v);
    }
    if (t == 0) hrow[NCB] = nseg;
    __syncthreads();
    // pass 2: scatter into LDS (bucket-ordered within block)
    for (int j = t; j < nseg; j += 256) {
        int e = base + j;
        int sv, d;
        if (e < Ee) { sv = src[e]; d = dst[e]; } else { sv = e - Ee; d = sv; }
        int pos = atomicAdd(&lh[d >> 10], 1);
        pbuf[pos] = (unsigned)sv | ((unsigned)(d & 1023) << 18);
    }
    __syncthreads();
    // pass 3: straight coalesced drain, block-major
    for (int j = t; j < nseg; j += 256)
        bucketed[base + j] = pbuf[j];
}

// Scan coarse totals -> cbase.
__global__ __launch_bounds__(256) void k_scan(
    const int* __restrict__ ctot, int* __restrict__ cbase,
    int* __restrict__ row_ptr)
{
    __shared__ int s[256];
    int t = threadIdx.x;
    int v = (t < NCB) ? ctot[t] : 0;
    s[t] = v; __syncthreads();
    for (int off = 1; off < 256; off <<= 1) {
        int u = (t >= off) ? s[t - off] : 0;
        __syncthreads();
        s[t] += u;
        __syncthreads();
    }
    if (t < NCB) cbase[t] = s[t] - v;
    if (t == 0) { cbase[NCB] = EP; row_ptr[Nn] = EP; }
}

// Phase B: ONE 1024-thread block per coarse bucket. R4: both passes are
// latency-optimized (run bounds preloaded to LDS, 4-way run pipelining =
// 4 outstanding gathers/wave); histogram is back in-kernel via LDS atomics
// (R3's global-atomic degree path cost 200 MB of HBM RMW — reverted).
__global__ __launch_bounds__(1024) void kB_csr(
    const unsigned* __restrict__ bucketed, const int* __restrict__ histT,
    const int* __restrict__ cbase, int* __restrict__ row_ptr,
    int* __restrict__ csr_src)
{
    __shared__ int2 hb[NBLKA];            // 6.4 KB run bounds
    __shared__ int bh[1024];              // hist -> excl scan -> cursors
    __shared__ unsigned pbuf[CAPB];       // 144 KB (158 KB total; 196 blocks -> 1/CU)
    const int k = blockIdx.x;
    const int t = threadIdx.x;
    const int w = t >> 6, lane = t & 63;  // 16 waves
    bh[t] = 0;
    // preload run bounds for this bucket (column k of histT)
    for (int j = t; j < NBLKA; j += 1024) {
        const int* hrow = histT + (size_t)j * HTS + k;
        hb[j] = make_int2(hrow[0], hrow[1]);
    }
    __syncthreads();
    // pass 1: 1024-bin histogram, 4 runs in flight per wave
    for (int b = w; b < NBLKA; b += 16 * 4) {
        int2 es[4]; unsigned ps[4];
#pragma unroll
        for (int u = 0; u < 4; ++u) {
            int bb = b + 16 * u;
            int2 e = (bb < NBLKA) ? hb[bb] : make_int2(0, 0);
            es[u] = e;
            int j = e.x + lane;
            ps[u] = (j < e.y)
                ? __builtin_nontemporal_load(bucketed + (size_t)bb * EPB + j)
                : 0u;
        }
#pragma unroll
        for (int u = 0; u < 4; ++u) {
            int bb = b + 16 * u;
            if (bb >= NBLKA) break;
            int j = es[u].x + lane;
            if (j < es[u].y) atomicAdd(&bh[(ps[u] >> 18) & 1023], 1);
            for (j += 64; j < es[u].y; j += 64) {   // rare (run > 64)
                unsigned p = __builtin_nontemporal_load(
                    bucketed + (size_t)bb * EPB + j);
                atomicAdd(&bh[(p >> 18) & 1023], 1);
            }
        }
    }
    __syncthreads();
    // exclusive scan of the 1024 bins (in place)
    int v = bh[t];
    for (int off = 1; off < 1024; off <<= 1) {
        int u = (t >= off) ? bh[t - off] : 0;
        __syncthreads();
        bh[t] += u;
        __syncthreads();
    }
    const int base_k = cbase[k];
    const int nseg_b = cbase[k + 1] - base_k;
    int ex = bh[t] - v;                   // exclusive, bucket-relative
    const int node = (k << 10) + t;
    if (node < Nn) row_ptr[node] = base_k + ex;
    bh[t] = ex;                           // own-slot overwrite -> cursor
    __syncthreads();
    const bool fit = (nseg_b <= CAPB);
    if (fit) {
        // pass 2: scatter into LDS pbuf, 4 runs in flight per wave
        for (int b = w; b < NBLKA; b += 16 * 4) {
            int2 es[4]; unsigned ps[4];
#pragma unroll
            for (int u = 0; u < 4; ++u) {
                int bb = b + 16 * u;
                int2 e = (bb < NBLKA) ? hb[bb] : make_int2(0, 0);
                es[u] = e;
                int j = e.x + lane;
                ps[u] = (j < e.y)
                    ? __builtin_nontemporal_load(bucketed + (size_t)bb * EPB + j)
                    : 0u;
            }
#pragma unroll
            for (int u = 0; u < 4; ++u) {
                int bb = b + 16 * u;
                if (bb >= NBLKA) break;
                int j = es[u].x + lane;
                if (j < es[u].y) {
                    unsigned p = ps[u];
                    int pos = atomicAdd(&bh[(p >> 18) & 1023], 1);
                    pbuf[pos] = p & 0x3FFFFu;
                }
                for (j += 64; j < es[u].y; j += 64) {   // rare (run > 64)
                    unsigned p = __builtin_nontemporal_load(
                        bucketed + (size_t)bb * EPB + j);
                    int pos = atomicAdd(&bh[(p >> 18) & 1023], 1);
                    pbuf[pos] = p & 0x3FFFFu;
                }
            }
        }
        __syncthreads();
        // fully-coalesced drain
        for (int j = t; j < nseg_b; j += 1024)
            csr_src[base_k + j] = (int)pbuf[j];
    } else {
        // fallback: direct global scatter (correct, slower; statistically never)
        for (int b = w; b < NBLKA; b += 16) {
            int2 e = hb[b];
            int rb = b * EPB;
            for (int j = e.x + lane; j < e.y; j += 64) {
                unsigned p = bucketed[rb + j];
                int pos = base_k + atomicAdd(&bh[(p >> 18) & 1023], 1);
                csr_src[pos] = (int)(p & 0x3FFFFu);
            }
        }
    }
}

// ============ per-layer kernels ============

// Gather-table layout (L2-resident: 3.6 MB total < 4 MB per-XCD L2):
//   A[i]  : 16 B  = h0..h7 as 4x half2              (3.2 MB)
//   Bh[i] :  2 B  = h8 as half                      (0.4 MB)
//   D[i]  :  4 B  = alpha_d fp32 (read per NODE)    (0.8 MB)
// alpha_s is NOT stored: recomputed per edge from the gathered fp16 h.
__global__ __launch_bounds__(256) void k_transform(
    const float* __restrict__ xin, int xstride,
    const float* __restrict__ Wl,
    const float* __restrict__ adst,
    float4* __restrict__ A, __half* __restrict__ Bh, float* __restrict__ D)
{
    int i = blockIdx.x * blockDim.x + threadIdx.x;
    if (i >= Nn) return;
    const float* xp = xin + (size_t)i * xstride;
    float xi[Hh];
#pragma unroll
    for (int k = 0; k < Hh; ++k) xi[k] = xp[k];
    float hv[Hh];
#pragma unroll
    for (int j = 0; j < Hh; ++j) {
        float s = 0.f;
#pragma unroll
        for (int k = 0; k < Hh; ++k) s += xi[k] * Wl[k * Hh + j];
        hv[j] = s;
    }
    float ad = 0.f;
#pragma unroll
    for (int j = 0; j < Hh; ++j) ad += hv[j] * adst[j];
    H2F u01, u23, u45, u67;
    u01.h = __floats2half2_rn(hv[0], hv[1]);
    u23.h = __floats2half2_rn(hv[2], hv[3]);
    u45.h = __floats2half2_rn(hv[4], hv[5]);
    u67.h = __floats2half2_rn(hv[6], hv[7]);
    A[i] = make_float4(u01.f, u23.f, u45.f, u67.f);
    Bh[i] = __float2half(hv[8]);
    D[i] = ad;
}

// Oct-per-node gather with LDS-staged CSR, 2-deep software-pipelined gathers.
// Single-pass softmax: |logits| << 88 so exp never overflows; ratio exact.
__global__ __launch_bounds__(256) void k_node_agg(
    const int* __restrict__ rp, const int* __restrict__ csr,
    const float4* __restrict__ A, const __half* __restrict__ Bh,
    const float* __restrict__ D, const float* __restrict__ asrc,
    const float* __restrict__ biasl,
    float* __restrict__ jk, int l)
{
    __shared__ int scsr[CAP];
    __shared__ int srp[NPB + 1];
    const int nbase = blockIdx.x * NPB;
    const int t = threadIdx.x;
    if (t <= NPB) srp[t] = rp[nbase + t];   // nbase+NPB <= Nn; rp[Nn] = EP
    __syncthreads();
    const int beg_blk = srp[0];
    const int nseg = srp[NPB] - beg_blk;
    const bool use_lds = (nseg <= CAP);
    if (use_lds)
        for (int j = t; j < nseg; j += 256)
            scsr[j] = __builtin_nontemporal_load(csr + beg_blk + j); // streamed
    __syncthreads();

    // att_src for this layer (uniform -> SGPRs)
    const float s0 = asrc[0], s1 = asrc[1], s2 = asrc[2], s3 = asrc[3],
                s4 = asrc[4], s5 = asrc[5], s6 = asrc[6], s7 = asrc[7],
                s8 = asrc[8];

    const int ni = t >> 3;          // node within block
    const int q  = t & 7;           // lane within oct
    const int i  = nbase + ni;
    const float c = D[i];           // own alpha_d (fp32, once per node)
    float a0=0,a1=0,a2=0,a3=0,a4=0,a5=0,a6=0,a7=0,a8=0,den=0;
    if (use_lds) {
        int idx = srp[ni] - beg_blk + q;
        const int iend = srp[ni + 1] - beg_blk;
        int s = (idx < iend) ? scsr[idx] : 0;
        float4 F = A[s];                    // prime the pipeline (s=0 is valid)
        __half hb = Bh[s];
        while (idx < iend) {
            int nidx = idx + 8;
            int sn = (nidx < iend) ? scsr[nidx] : 0;
            float4 Fn = A[sn];              // issue next gather BEFORE using F
            __half hbn = Bh[sn];
            H2F u; float2 p;
            u.f = F.x; p = __half22float2(u.h); float x0 = p.x, x1 = p.y;
            u.f = F.y; p = __half22float2(u.h); float x2 = p.x, x3 = p.y;
            u.f = F.z; p = __half22float2(u.h); float x4 = p.x, x5 = p.y;
            u.f = F.w; p = __half22float2(u.h); float x6 = p.x, x7 = p.y;
            float x8 = __half2float(hb);
            float as = x0*s0 + x1*s1 + x2*s2 + x3*s3 + x4*s4
                     + x5*s5 + x6*s6 + x7*s7 + x8*s8;
            float lg = as + c;
            lg = lg > 0.f ? lg : 0.2f * lg;            // leaky_relu(0.2)
            float w = __expf(lg);
            a0 += w*x0; a1 += w*x1; a2 += w*x2; a3 += w*x3; a4 += w*x4;
            a5 += w*x5; a6 += w*x6; a7 += w*x7; a8 += w*x8;
            den += w;
            F = Fn; hb = hbn; idx = nidx;
        }
    } else {
        for (int e = srp[ni] + q; e < srp[ni + 1]; e += 8) {
            int s = csr[e];
            float4 F = A[s];
            __half hb = Bh[s];
            H2F u; float2 p;
            u.f = F.x; p = __half22float2(u.h); float x0 = p.x, x1 = p.y;
            u.f = F.y; p = __half22float2(u.h); float x2 = p.x, x3 = p.y;
            u.f = F.z; p = __half22float2(u.h); float x4 = p.x, x5 = p.y;
            u.f = F.w; p = __half22float2(u.h); float x6 = p.x, x7 = p.y;
            float x8 = __half2float(hb);
            float as = x0*s0 + x1*s1 + x2*s2 + x3*s3 + x4*s4
                     + x5*s5 + x6*s6 + x7*s7 + x8*s8;
            float lg = as + c;
            lg = lg > 0.f ? lg : 0.2f * lg;
            float w = __expf(lg);
            a0 += w*x0; a1 += w*x1; a2 += w*x2; a3 += w*x3; a4 += w*x4;
            a5 += w*x5; a6 += w*x6; a7 += w*x7; a8 += w*x8;
            den += w;
        }
    }
#pragma unroll
    for (int m = 1; m <= 4; m <<= 1) {
        a0 += __shfl_xor(a0, m); a1 += __shfl_xor(a1, m);
        a2 += __shfl_xor(a2, m); a3 += __shfl_xor(a3, m);
        a4 += __shfl_xor(a4, m); a5 += __shfl_xor(a5, m);
        a6 += __shfl_xor(a6, m); a7 += __shfl_xor(a7, m);
        a8 += __shfl_xor(a8, m); den += __shfl_xor(den, m);
    }
    if (q == 0) {
        float inv = 1.f / den;          // den >= 1 (self-loop term)
        float* jp = jk + (size_t)i * JK + l * Hh;
        float o;
        o = fmaxf(a0*inv + biasl[0], 0.f); __builtin_nontemporal_store(o, jp + 0);
        o = fmaxf(a1*inv + biasl[1], 0.f); __builtin_nontemporal_store(o, jp + 1);
        o = fmaxf(a2*inv + biasl[2], 0.f); __builtin_nontemporal_store(o, jp + 2);
        o = fmaxf(a3*inv + biasl[3], 0.f); __builtin_nontemporal_store(o, jp + 3);
        o = fmaxf(a4*inv + biasl[4], 0.f); __builtin_nontemporal_store(o, jp + 4);
        o = fmaxf(a5*inv + biasl[5], 0.f); __builtin_nontemporal_store(o, jp + 5);
        o = fmaxf(a6*inv + biasl[6], 0.f); __builtin_nontemporal_store(o, jp + 6);
        o = fmaxf(a7*inv + biasl[7], 0.f); __builtin_nontemporal_store(o, jp + 7);
        o = fmaxf(a8*inv + biasl[8], 0.f); __builtin_nontemporal_store(o, jp + 8);
    }
}

// ============ pool + fc ============

// batch is sorted -> graphs are contiguous node ranges. Build range starts.
__global__ __launch_bounds__(256) void k_graph_ptr(
    const int* __restrict__ batch, int* __restrict__ gp)
{
    int i = blockIdx.x * 256 + threadIdx.x;
    if (i >= Nn) return;
    int b = batch[i];
    if (i == 0) {
        for (int g = 0; g <= b; ++g) gp[g] = 0;
    } else {
        int pb = batch[i - 1];
        for (int g = pb + 1; g <= b; ++g) gp[g] = i;
    }
    if (i == Nn - 1) {
        for (int g = b + 1; g <= Gg; ++g) gp[g] = Nn;
    }
}

// Segmented max, one thread per (graph, col). Post-relu values >= 0 and
// init 0 reproduces the isfinite->0 guard for empty graphs.
__global__ __launch_bounds__(256) void k_pool_seg(
    const float* __restrict__ jk, const int* __restrict__ gp,
    float* __restrict__ pooled)
{
    int t = blockIdx.x * 256 + threadIdx.x;
    if (t >= Gg * JK) return;
    int g = t / JK, col = t - g * JK;
    int beg = gp[g], end = gp[g + 1];
    float m = 0.f;
    for (int i = beg; i < end; ++i)
        m = fmaxf(m, jk[(size_t)i * JK + col]);
    pooled[t] = m;
}

__global__ __launch_bounds__(256) void k_fc(
    const float* __restrict__ pooled, const float* __restrict__ fcw,
    const float* __restrict__ fcb, float* __restrict__ out)
{
    int t = blockIdx.x * blockDim.x + threadIdx.x;
    if (t >= Gg * Cc) return;
    int g = t / Cc, c = t - g * Cc;
    float s = fcb[c];
    const float* pp = pooled + (size_t)g * JK;
#pragma unroll
    for (int j = 0; j < JK; ++j) s += pp[j] * fcw[j * Cc + c];
    out[t] = s;
}

extern "C" void kernel_launch(void* const* d_in, const int* in_sizes, int n_in,
                              void* d_out, int out_size, void* d_ws, size_t ws_size,
                              hipStream_t stream) {
    const float* x      = (const float*)d_in[0];   // [N,9]
    const int*   ei     = (const int*)d_in[1];     // [2,E]: src row then dst row
    const int*   batch  = (const int*)d_in[2];     // [N] sorted
    const float* W      = (const float*)d_in[3];   // [L,9,9]
    const float* a_src  = (const float*)d_in[4];   // [L,9]
    const float* a_dst  = (const float*)d_in[5];   // [L,9]
    const float* bias   = (const float*)d_in[6];   // [L,9]
    const float* fc_w   = (const float*)d_in[7];   // [36,2]
    const float* fc_b   = (const float*)d_in[8];   // [2]
    float* out = (float*)d_out;

    // Workspace layout (~61 MB live). histT aliases A, bucketed aliases jk —
    // both dead before A/jk are first written (same-stream ordering).
    float* ws        = (float*)d_ws;
    float4* A        = (float4*)ws;                       // Nn*16B (3.2MB)
    __half* Bh       = (__half*)(ws + (size_t)Nn * 4);    // Nn*2B  (0.4MB)
    float* D         = (float*)((char*)Bh + (size_t)Nn * sizeof(__half)); // Nn*4B
    float* jk        = D + Nn;                            // Nn*JK (28.8MB)
    float* pooled    = jk + (size_t)Nn * JK;              // Gg*JK
    int* row_ptr     = (int*)(pooled + (size_t)Gg * JK);  // Nn+1
    int* gp          = row_ptr + Nn + 1;                  // Gg+1
    int* ctot        = gp + Gg + 1;                       // NCB
    int* cbase       = ctot + NCB;                        // NCB+1
    int* csr_src     = cbase + NCB + 1;                   // EP (26.4MB)
    int* histT       = (int*)ws;                          // aliases A (0.64MB)
    unsigned* bucketed = (unsigned*)jk;                   // EP alias (26.4MB)

    const int* srcp = ei;
    const int* dstp = ei + Ee;

    // CSR build (edge structure is layer-invariant)
    hipMemsetAsync(ctot, 0, NCB * sizeof(int), stream);
    kA_scatter<<<NBLKA, 256, 0, stream>>>(srcp, dstp, ctot, histT, bucketed);
    k_scan    <<<1, 256, 0, stream>>>(ctot, cbase, row_ptr);
    kB_csr    <<<NCB, 1024, 0, stream>>>(bucketed, histT, cbase, row_ptr, csr_src);

    for (int l = 0; l < Ll; ++l) {
        const float* xin = (l == 0) ? x : (jk + (size_t)(l - 1) * Hh);
        int xstride      = (l == 0) ? Hh : JK;
        k_transform<<<NB, 256, 0, stream>>>(xin, xstride, W + l * Hh * Hh,
                                            a_dst + l * Hh, A, Bh, D);
        k_node_agg<<<NAB, 256, 0, stream>>>(row_ptr, csr_src, A, Bh, D,
                                            a_src + l * Hh, bias + l * Hh, jk, l);
    }
    k_graph_ptr<<<NB, 256, 0, stream>>>(batch, gp);
    k_pool_seg<<<(Gg * JK + 255) / 256, 256, 0, stream>>>(jk, gp, pooled);
    k_fc<<<(Gg * Cc + 255) / 256, 256, 0, stream>>>(pooled, fc_w, fc_b, out);
}

// Round 5
// 523.954 us; speedup vs baseline: 1.4037x; 1.0612x over previous
//
#include <hip/hip_runtime.h>
#include <hip/hip_fp16.h>

// Problem constants (from reference)
#define Nn 200000
#define Ee 6400000
#define EP 6600000            // Ee + Nn self loops
#define Hh 9
#define Ll 4
#define Gg 2000
#define Cc 2
#define JK 36                 // Ll * Hh
#define NCB ((Nn + 1023) >> 10) // 196 coarse buckets (1024 nodes each)
#define EPB 8192              // edges per phase-A block
#define NBLKA ((EP + EPB - 1) / EPB) // 806
#define NB ((Nn + 255) / 256) // 782
#define NPB 32                // nodes per k_node_agg block (oct per node)
#define NAB (Nn / NPB)        // 6250 blocks
#define CAP 3072              // staged csr entries per block (12 KB)
#define CAPB 36864            // kB_csr staged entries (144 KB; mean 33792 + 17 sigma)
#define HTS (NCB + 1)         // histT row stride

union H2F { __half2 h; float f; };

// ========= CSR build: block-major multisplit + per-bucket LDS sort =========

// Phase A: per-block LDS multisplit, drained BLOCK-MAJOR (straight coalesced
// copy). Per-block bucket offsets -> histT row; global bucket totals -> ctot
// (196 LDS-aggregated atomics/block — NOT per-edge; R3 lesson: per-edge
// global atomics cost ~30B HBM each).
// Payload: src (18b) | dst low 10 bits << 18.
__global__ __launch_bounds__(256) void kA_scatter(
    const int* __restrict__ src, const int* __restrict__ dst,
    int* __restrict__ ctot, int* __restrict__ histT,
    unsigned* __restrict__ bucketed)
{
    __shared__ unsigned pbuf[EPB];        // 32 KB
    __shared__ int lh[NCB];
    __shared__ int s[256];
    int t = threadIdx.x;
    if (t < NCB) lh[t] = 0;
    __syncthreads();
    const int base = blockIdx.x * EPB;
    const int nseg = min(EPB, EP - base);
    // pass 1: coarse histogram (dst only)
    for (int j = t; j < nseg; j += 256) {
        int e = base + j;
        int d = (e < Ee) ? dst[e] : (e - Ee);
        atomicAdd(&lh[d >> 10], 1);
    }
    __syncthreads();
    // exclusive scan of 196 bins
    int v = (t < NCB) ? lh[t] : 0;
    s[t] = v; __syncthreads();
    for (int off = 1; off < 256; off <<= 1) {
        int u = (t >= off) ? s[t - off] : 0;
        __syncthreads();
        s[t] += u;
        __syncthreads();
    }
    int* hrow = histT + (size_t)blockIdx.x * HTS;
    if (t < NCB) {
        int ex = s[t] - v;
        lh[t] = ex;                        // LDS cursor
        hrow[t] = ex;                      // run starts for kB
        if (v) atomicAdd(&ctot[t], v);
    }
    if (t == 0) hrow[NCB] = nseg;
    __syncthreads();
    // pass 2: scatter into LDS (bucket-ordered within block)
    for (int j = t; j < nseg; j += 256) {
        int e = base + j;
        int sv, d;
        if (e < Ee) { sv = src[e]; d = dst[e]; } else { sv = e - Ee; d = sv; }
        int pos = atomicAdd(&lh[d >> 10], 1);
        pbuf[pos] = (unsigned)sv | ((unsigned)(d & 1023) << 18);
    }
    __syncthreads();
    // pass 3: straight coalesced drain, block-major
    for (int j = t; j < nseg; j += 256)
        bucketed[base + j] = pbuf[j];
}

// Scan coarse totals -> cbase.
__global__ __launch_bounds__(256) void k_scan(
    const int* __restrict__ ctot, int* __restrict__ cbase,
    int* __restrict__ row_ptr)
{
    __shared__ int s[256];
    int t = threadIdx.x;
    int v = (t < NCB) ? ctot[t] : 0;
    s[t] = v; __syncthreads();
    for (int off = 1; off < 256; off <<= 1) {
        int u = (t >= off) ? s[t - off] : 0;
        __syncthreads();
        s[t] += u;
        __syncthreads();
    }
    if (t < NCB) cbase[t] = s[t] - v;
    if (t == 0) { cbase[NCB] = EP; row_ptr[Nn] = EP; }
}

// Phase B: ONE 1024-thread block per coarse bucket. Both passes are
// latency-optimized (run bounds preloaded to LDS, 4-way run pipelining =
// 4 outstanding gathers/wave); histogram in-kernel via LDS atomics.
__global__ __launch_bounds__(1024) void kB_csr(
    const unsigned* __restrict__ bucketed, const int* __restrict__ histT,
    const int* __restrict__ cbase, int* __restrict__ row_ptr,
    int* __restrict__ csr_src)
{
    __shared__ int2 hb[NBLKA];            // 6.4 KB run bounds
    __shared__ int bh[1024];              // hist -> excl scan -> cursors
    __shared__ unsigned pbuf[CAPB];       // 144 KB (158 KB total; 196 blocks -> 1/CU)
    const int k = blockIdx.x;
    const int t = threadIdx.x;
    const int w = t >> 6, lane = t & 63;  // 16 waves
    bh[t] = 0;
    // preload run bounds for this bucket (column k of histT)
    for (int j = t; j < NBLKA; j += 1024) {
        const int* hrow = histT + (size_t)j * HTS + k;
        hb[j] = make_int2(hrow[0], hrow[1]);
    }
    __syncthreads();
    // pass 1: 1024-bin histogram, 4 runs in flight per wave
    for (int b = w; b < NBLKA; b += 16 * 4) {
        int2 es[4]; unsigned ps[4];
#pragma unroll
        for (int u = 0; u < 4; ++u) {
            int bb = b + 16 * u;
            int2 e = (bb < NBLKA) ? hb[bb] : make_int2(0, 0);
            es[u] = e;
            int j = e.x + lane;
            ps[u] = (j < e.y)
                ? __builtin_nontemporal_load(bucketed + (size_t)bb * EPB + j)
                : 0u;
        }
#pragma unroll
        for (int u = 0; u < 4; ++u) {
            int bb = b + 16 * u;
            if (bb >= NBLKA) break;
            int j = es[u].x + lane;
            if (j < es[u].y) atomicAdd(&bh[(ps[u] >> 18) & 1023], 1);
            for (j += 64; j < es[u].y; j += 64) {   // rare (run > 64)
                unsigned p = __builtin_nontemporal_load(
                    bucketed + (size_t)bb * EPB + j);
                atomicAdd(&bh[(p >> 18) & 1023], 1);
            }
        }
    }
    __syncthreads();
    // exclusive scan of the 1024 bins (in place)
    int v = bh[t];
    for (int off = 1; off < 1024; off <<= 1) {
        int u = (t >= off) ? bh[t - off] : 0;
        __syncthreads();
        bh[t] += u;
        __syncthreads();
    }
    const int base_k = cbase[k];
    const int nseg_b = cbase[k + 1] - base_k;
    int ex = bh[t] - v;                   // exclusive, bucket-relative
    const int node = (k << 10) + t;
    if (node < Nn) row_ptr[node] = base_k + ex;
    bh[t] = ex;                           // own-slot overwrite -> cursor
    __syncthreads();
    const bool fit = (nseg_b <= CAPB);
    if (fit) {
        // pass 2: scatter into LDS pbuf, 4 runs in flight per wave
        for (int b = w; b < NBLKA; b += 16 * 4) {
            int2 es[4]; unsigned ps[4];
#pragma unroll
            for (int u = 0; u < 4; ++u) {
                int bb = b + 16 * u;
                int2 e = (bb < NBLKA) ? hb[bb] : make_int2(0, 0);
                es[u] = e;
                int j = e.x + lane;
                ps[u] = (j < e.y)
                    ? __builtin_nontemporal_load(bucketed + (size_t)bb * EPB + j)
                    : 0u;
            }
#pragma unroll
            for (int u = 0; u < 4; ++u) {
                int bb = b + 16 * u;
                if (bb >= NBLKA) break;
                int j = es[u].x + lane;
                if (j < es[u].y) {
                    unsigned p = ps[u];
                    int pos = atomicAdd(&bh[(p >> 18) & 1023], 1);
                    pbuf[pos] = p & 0x3FFFFu;
                }
                for (j += 64; j < es[u].y; j += 64) {   // rare (run > 64)
                    unsigned p = __builtin_nontemporal_load(
                        bucketed + (size_t)bb * EPB + j);
                    int pos = atomicAdd(&bh[(p >> 18) & 1023], 1);
                    pbuf[pos] = p & 0x3FFFFu;
                }
            }
        }
        __syncthreads();
        // fully-coalesced drain
        for (int j = t; j < nseg_b; j += 1024)
            csr_src[base_k + j] = (int)pbuf[j];
    } else {
        // fallback: direct global scatter (correct, slower; statistically never)
        for (int b = w; b < NBLKA; b += 16) {
            int2 e = hb[b];
            int rb = b * EPB;
            for (int j = e.x + lane; j < e.y; j += 64) {
                unsigned p = bucketed[rb + j];
                int pos = base_k + atomicAdd(&bh[(p >> 18) & 1023], 1);
                csr_src[pos] = (int)(p & 0x3FFFFu);
            }
        }
    }
}

// ============ per-layer kernels ============

// Gather-table layout (L2-resident: 3.6 MB total < 4 MB per-XCD L2):
//   A[i]  : 16 B  = h0..h7 as 4x half2              (3.2 MB)
//   Bh[i] :  2 B  = h8 as half                      (0.4 MB)
//   D[i]  :  4 B  = alpha_d fp32 (read per NODE)    (0.8 MB)
// alpha_s is NOT stored: recomputed per edge from the gathered fp16 h.
// jk is LAYER-MAJOR [L][Nn][9] (R5): agg writes and transform reads are
// contiguous -> no partial-line write/read amplification.
__global__ __launch_bounds__(256) void k_transform(
    const float* __restrict__ xin, int xstride,
    const float* __restrict__ Wl,
    const float* __restrict__ adst,
    float4* __restrict__ A, __half* __restrict__ Bh, float* __restrict__ D)
{
    int i = blockIdx.x * blockDim.x + threadIdx.x;
    if (i >= Nn) return;
    const float* xp = xin + (size_t)i * xstride;
    float xi[Hh];
#pragma unroll
    for (int k = 0; k < Hh; ++k) xi[k] = xp[k];
    float hv[Hh];
#pragma unroll
    for (int j = 0; j < Hh; ++j) {
        float s = 0.f;
#pragma unroll
        for (int k = 0; k < Hh; ++k) s += xi[k] * Wl[k * Hh + j];
        hv[j] = s;
    }
    float ad = 0.f;
#pragma unroll
    for (int j = 0; j < Hh; ++j) ad += hv[j] * adst[j];
    H2F u01, u23, u45, u67;
    u01.h = __floats2half2_rn(hv[0], hv[1]);
    u23.h = __floats2half2_rn(hv[2], hv[3]);
    u45.h = __floats2half2_rn(hv[4], hv[5]);
    u67.h = __floats2half2_rn(hv[6], hv[7]);
    A[i] = make_float4(u01.f, u23.f, u45.f, u67.f);
    Bh[i] = __float2half(hv[8]);
    D[i] = ad;
}

// Per-edge math, shared by both agg paths.
#define AGG_EDGE(F, HB)                                                     \
    {                                                                       \
        H2F u; float2 p;                                                    \
        u.f = (F).x; p = __half22float2(u.h); float x0 = p.x, x1 = p.y;     \
        u.f = (F).y; p = __half22float2(u.h); float x2 = p.x, x3 = p.y;     \
        u.f = (F).z; p = __half22float2(u.h); float x4 = p.x, x5 = p.y;     \
        u.f = (F).w; p = __half22float2(u.h); float x6 = p.x, x7 = p.y;     \
        float x8 = __half2float(HB);                                        \
        float as = x0*s0 + x1*s1 + x2*s2 + x3*s3 + x4*s4                    \
                 + x5*s5 + x6*s6 + x7*s7 + x8*s8;                           \
        float lg = as + c;                                                  \
        lg = lg > 0.f ? lg : 0.2f * lg;                                     \
        float wgt = __expf(lg);                                             \
        a0 += wgt*x0; a1 += wgt*x1; a2 += wgt*x2; a3 += wgt*x3;             \
        a4 += wgt*x4; a5 += wgt*x5; a6 += wgt*x6; a7 += wgt*x7;             \
        a8 += wgt*x8; den += wgt;                                           \
    }

// Oct-per-node gather with LDS-staged CSR. R5: TWO independent 2-deep
// pipelines per lane (edges idx,idx+16,.. and idx+8,idx+24,..) = 4
// outstanding random loads/lane — the R4 counters showed MLP-limited
// latency (9% HBM BW, 21% VALU, ~70% occupancy, all waves stalled).
// Single-pass softmax: |logits| << 88 so exp never overflows; ratio exact.
__global__ __launch_bounds__(256) void k_node_agg(
    const int* __restrict__ rp, const int* __restrict__ csr,
    const float4* __restrict__ A, const __half* __restrict__ Bh,
    const float* __restrict__ D, const float* __restrict__ asrc,
    const float* __restrict__ biasl,
    float* __restrict__ jk, int l)
{
    __shared__ int scsr[CAP];
    __shared__ int srp[NPB + 1];
    const int nbase = blockIdx.x * NPB;
    const int t = threadIdx.x;
    if (t <= NPB) srp[t] = rp[nbase + t];   // nbase+NPB <= Nn; rp[Nn] = EP
    __syncthreads();
    const int beg_blk = srp[0];
    const int nseg = srp[NPB] - beg_blk;
    const bool use_lds = (nseg <= CAP);
    if (use_lds)
        for (int j = t; j < nseg; j += 256)
            scsr[j] = __builtin_nontemporal_load(csr + beg_blk + j); // streamed
    __syncthreads();

    // att_src for this layer (uniform -> SGPRs)
    const float s0 = asrc[0], s1 = asrc[1], s2 = asrc[2], s3 = asrc[3],
                s4 = asrc[4], s5 = asrc[5], s6 = asrc[6], s7 = asrc[7],
                s8 = asrc[8];

    const int ni = t >> 3;          // node within block
    const int q  = t & 7;           // lane within oct
    const int i  = nbase + ni;
    const float c = D[i];           // own alpha_d (fp32, once per node)
    float a0=0,a1=0,a2=0,a3=0,a4=0,a5=0,a6=0,a7=0,a8=0,den=0;
    if (use_lds) {
        const int iend = srp[ni + 1] - beg_blk;
        int i0 = srp[ni] - beg_blk + q;
        int i1 = i0 + 8;
        int sv0 = (i0 < iend) ? scsr[i0] : 0;   // s=0 fallback: valid addr
        int sv1 = (i1 < iend) ? scsr[i1] : 0;
        float4 F0 = A[sv0]; __half b0 = Bh[sv0];
        float4 F1 = A[sv1]; __half b1 = Bh[sv1];
        while (i0 < iend) {
            int n0 = i0 + 16, n1 = i1 + 16;
            int sn0 = (n0 < iend) ? scsr[n0] : 0;
            int sn1 = (n1 < iend) ? scsr[n1] : 0;
            float4 Fn0 = A[sn0]; __half bn0 = Bh[sn0];  // issue 4 loads
            float4 Fn1 = A[sn1]; __half bn1 = Bh[sn1];  // before consuming
            AGG_EDGE(F0, b0);
            if (i1 < iend) AGG_EDGE(F1, b1);
            F0 = Fn0; b0 = bn0; F1 = Fn1; b1 = bn1;
            i0 = n0; i1 = n1;
        }
    } else {
        for (int e = srp[ni] + q; e < srp[ni + 1]; e += 8) {
            int s = csr[e];
            float4 F = A[s];
            __half hb = Bh[s];
            AGG_EDGE(F, hb);
        }
    }
#pragma unroll
    for (int m = 1; m <= 4; m <<= 1) {
        a0 += __shfl_xor(a0, m); a1 += __shfl_xor(a1, m);
        a2 += __shfl_xor(a2, m); a3 += __shfl_xor(a3, m);
        a4 += __shfl_xor(a4, m); a5 += __shfl_xor(a5, m);
        a6 += __shfl_xor(a6, m); a7 += __shfl_xor(a7, m);
        a8 += __shfl_xor(a8, m); den += __shfl_xor(den, m);
    }
    if (q == 0) {
        float inv = 1.f / den;          // den >= 1 (self-loop term)
        // layer-major jk: contiguous 36B per node -> coalesced, L2-merged
        float* jp = jk + (size_t)l * Nn * Hh + (size_t)i * Hh;
        jp[0] = fmaxf(a0*inv + biasl[0], 0.f);
        jp[1] = fmaxf(a1*inv + biasl[1], 0.f);
        jp[2] = fmaxf(a2*inv + biasl[2], 0.f);
        jp[3] = fmaxf(a3*inv + biasl[3], 0.f);
        jp[4] = fmaxf(a4*inv + biasl[4], 0.f);
        jp[5] = fmaxf(a5*inv + biasl[5], 0.f);
        jp[6] = fmaxf(a6*inv + biasl[6], 0.f);
        jp[7] = fmaxf(a7*inv + biasl[7], 0.f);
        jp[8] = fmaxf(a8*inv + biasl[8], 0.f);
    }
}

// ============ pool + fc ============

// batch is sorted -> graphs are contiguous node ranges. Build range starts.
__global__ __launch_bounds__(256) void k_graph_ptr(
    const int* __restrict__ batch, int* __restrict__ gp)
{
    int i = blockIdx.x * 256 + threadIdx.x;
    if (i >= Nn) return;
    int b = batch[i];
    if (i == 0) {
        for (int g = 0; g <= b; ++g) gp[g] = 0;
    } else {
        int pb = batch[i - 1];
        for (int g = pb + 1; g <= b; ++g) gp[g] = i;
    }
    if (i == Nn - 1) {
        for (int g = b + 1; g <= Gg; ++g) gp[g] = Nn;
    }
}

// Segmented max, one thread per (graph, col). jk is layer-major [L][Nn][9];
// pooled keeps concat order col = l*9+c. Post-relu values >= 0 and init 0
// reproduces the isfinite->0 guard for empty graphs.
__global__ __launch_bounds__(256) void k_pool_seg(
    const float* __restrict__ jk, const int* __restrict__ gp,
    float* __restrict__ pooled)
{
    int t = blockIdx.x * 256 + threadIdx.x;
    if (t >= Gg * JK) return;
    int g = t / JK, col = t - g * JK;
    int lc = col / Hh, cc = col - lc * Hh;
    const float* bp = jk + (size_t)lc * Nn * Hh + cc;
    int beg = gp[g], end = gp[g + 1];
    float m = 0.f;
    for (int i = beg; i < end; ++i)
        m = fmaxf(m, bp[(size_t)i * Hh]);
    pooled[t] = m;
}

__global__ __launch_bounds__(256) void k_fc(
    const float* __restrict__ pooled, const float* __restrict__ fcw,
    const float* __restrict__ fcb, float* __restrict__ out)
{
    int t = blockIdx.x * blockDim.x + threadIdx.x;
    if (t >= Gg * Cc) return;
    int g = t / Cc, c = t - g * Cc;
    float s = fcb[c];
    const float* pp = pooled + (size_t)g * JK;
#pragma unroll
    for (int j = 0; j < JK; ++j) s += pp[j] * fcw[j * Cc + c];
    out[t] = s;
}

extern "C" void kernel_launch(void* const* d_in, const int* in_sizes, int n_in,
                              void* d_out, int out_size, void* d_ws, size_t ws_size,
                              hipStream_t stream) {
    const float* x      = (const float*)d_in[0];   // [N,9]
    const int*   ei     = (const int*)d_in[1];     // [2,E]: src row then dst row
    const int*   batch  = (const int*)d_in[2];     // [N] sorted
    const float* W      = (const float*)d_in[3];   // [L,9,9]
    const float* a_src  = (const float*)d_in[4];   // [L,9]
    const float* a_dst  = (const float*)d_in[5];   // [L,9]
    const float* bias   = (const float*)d_in[6];   // [L,9]
    const float* fc_w   = (const float*)d_in[7];   // [36,2]
    const float* fc_b   = (const float*)d_in[8];   // [2]
    float* out = (float*)d_out;

    // Workspace layout (~61 MB live). histT aliases A, bucketed aliases jk —
    // both dead before A/jk are first written (same-stream ordering).
    float* ws        = (float*)d_ws;
    float4* A        = (float4*)ws;                       // Nn*16B (3.2MB)
    __half* Bh       = (__half*)(ws + (size_t)Nn * 4);    // Nn*2B  (0.4MB)
    float* D         = (float*)((char*)Bh + (size_t)Nn * sizeof(__half)); // Nn*4B
    float* jk        = D + Nn;                            // Nn*JK (28.8MB), layer-major
    float* pooled    = jk + (size_t)Nn * JK;              // Gg*JK
    int* row_ptr     = (int*)(pooled + (size_t)Gg * JK);  // Nn+1
    int* gp          = row_ptr + Nn + 1;                  // Gg+1
    int* ctot        = gp + Gg + 1;                       // NCB
    int* cbase       = ctot + NCB;                        // NCB+1
    int* csr_src     = cbase + NCB + 1;                   // EP (26.4MB)
    int* histT       = (int*)ws;                          // aliases A (0.64MB)
    unsigned* bucketed = (unsigned*)jk;                   // EP alias (26.4MB)

    const int* srcp = ei;
    const int* dstp = ei + Ee;

    // CSR build (edge structure is layer-invariant)
    hipMemsetAsync(ctot, 0, NCB * sizeof(int), stream);
    kA_scatter<<<NBLKA, 256, 0, stream>>>(srcp, dstp, ctot, histT, bucketed);
    k_scan    <<<1, 256, 0, stream>>>(ctot, cbase, row_ptr);
    kB_csr    <<<NCB, 1024, 0, stream>>>(bucketed, histT, cbase, row_ptr, csr_src);

    for (int l = 0; l < Ll; ++l) {
        const float* xin = (l == 0) ? x : (jk + (size_t)(l - 1) * Nn * Hh);
        int xstride      = Hh;   // input x and layer-major jk are both stride-9
        k_transform<<<NB, 256, 0, stream>>>(xin, xstride, W + l * Hh * Hh,
                                            a_dst + l * Hh, A, Bh, D);
        k_node_agg<<<NAB, 256, 0, stream>>>(row_ptr, csr_src, A, Bh, D,
                                            a_src + l * Hh, bias + l * Hh, jk, l);
    }
    k_graph_ptr<<<NB, 256, 0, stream>>>(batch, gp);
    k_pool_seg<<<(Gg * JK + 255) / 256, 256, 0, stream>>>(jk, gp, pooled);
    k_fc<<<(Gg * Cc + 255) / 256, 256, 0, stream>>>(pooled, fc_w, fc_b, out);
}

// Round 6
// 510.695 us; speedup vs baseline: 1.4402x; 1.0260x over previous
//
#include <hip/hip_runtime.h>
#include <hip/hip_fp16.h>

// Problem constants (from reference)
#define Nn 200000
#define Ee 6400000
#define EP 6600000            // Ee + Nn self loops
#define Hh 9
#define Ll 4
#define Gg 2000
#define Cc 2
#define JK 36                 // Ll * Hh
#define NCB ((Nn + 1023) >> 10) // 196 coarse buckets (1024 nodes each)
#define EPB 8192              // edges per phase-A block
#define NBLKA ((EP + EPB - 1) / EPB) // 806
#define NB ((Nn + 255) / 256) // 782
#define NPB 32                // nodes per k_node_agg block (oct per node)
#define NAB (Nn / NPB)        // 6250 blocks
#define CAP 3072              // staged csr entries per block (12 KB)
#define CAPB 36864            // kB_csr staged entries (144 KB; mean 33792 + 17 sigma)
#define HTS (NCB + 1)         // histT row stride

union H2F { __half2 h; float f; };

// ========= CSR build: block-major multisplit + per-bucket LDS sort =========

// Phase A: per-block LDS multisplit, drained BLOCK-MAJOR (straight coalesced
// copy). Per-block bucket offsets -> histT row; global bucket totals -> ctot
// (196 LDS-aggregated atomics/block — NOT per-edge; R3 lesson: per-edge
// global atomics cost ~30B HBM each).
// Payload: src (18b) | dst low 10 bits << 18.
__global__ __launch_bounds__(256) void kA_scatter(
    const int* __restrict__ src, const int* __restrict__ dst,
    int* __restrict__ ctot, int* __restrict__ histT,
    unsigned* __restrict__ bucketed)
{
    __shared__ unsigned pbuf[EPB];        // 32 KB
    __shared__ int lh[NCB];
    __shared__ int s[256];
    int t = threadIdx.x;
    if (t < NCB) lh[t] = 0;
    __syncthreads();
    const int base = blockIdx.x * EPB;
    const int nseg = min(EPB, EP - base);
    // pass 1: coarse histogram (dst only)
    for (int j = t; j < nseg; j += 256) {
        int e = base + j;
        int d = (e < Ee) ? dst[e] : (e - Ee);
        atomicAdd(&lh[d >> 10], 1);
    }
    __syncthreads();
    // exclusive scan of 196 bins
    int v = (t < NCB) ? lh[t] : 0;
    s[t] = v; __syncthreads();
    for (int off = 1; off < 256; off <<= 1) {
        int u = (t >= off) ? s[t - off] : 0;
        __syncthreads();
        s[t] += u;
        __syncthreads();
    }
    int* hrow = histT + (size_t)blockIdx.x * HTS;
    if (t < NCB) {
        int ex = s[t] - v;
        lh[t] = ex;                        // LDS cursor
        hrow[t] = ex;                      // run starts for kB
        if (v) atomicAdd(&ctot[t], v);
    }
    if (t == 0) hrow[NCB] = nseg;
    __syncthreads();
    // pass 2: scatter into LDS (bucket-ordered within block)
    for (int j = t; j < nseg; j += 256) {
        int e = base + j;
        int sv, d;
        if (e < Ee) { sv = src[e]; d = dst[e]; } else { sv = e - Ee; d = sv; }
        int pos = atomicAdd(&lh[d >> 10], 1);
        pbuf[pos] = (unsigned)sv | ((unsigned)(d & 1023) << 18);
    }
    __syncthreads();
    // pass 3: straight coalesced drain, block-major
    for (int j = t; j < nseg; j += 256)
        bucketed[base + j] = pbuf[j];
}

// Scan coarse totals -> cbase.
__global__ __launch_bounds__(256) void k_scan(
    const int* __restrict__ ctot, int* __restrict__ cbase,
    int* __restrict__ row_ptr)
{
    __shared__ int s[256];
    int t = threadIdx.x;
    int v = (t < NCB) ? ctot[t] : 0;
    s[t] = v; __syncthreads();
    for (int off = 1; off < 256; off <<= 1) {
        int u = (t >= off) ? s[t - off] : 0;
        __syncthreads();
        s[t] += u;
        __syncthreads();
    }
    if (t < NCB) cbase[t] = s[t] - v;
    if (t == 0) { cbase[NCB] = EP; row_ptr[Nn] = EP; }
}

// Phase B: ONE 1024-thread block per coarse bucket. Both passes are
// latency-optimized (run bounds preloaded to LDS, 4-way run pipelining =
// 4 outstanding gathers/wave); histogram in-kernel via LDS atomics.
__global__ __launch_bounds__(1024) void kB_csr(
    const unsigned* __restrict__ bucketed, const int* __restrict__ histT,
    const int* __restrict__ cbase, int* __restrict__ row_ptr,
    int* __restrict__ csr_src)
{
    __shared__ int2 hb[NBLKA];            // 6.4 KB run bounds
    __shared__ int bh[1024];              // hist -> excl scan -> cursors
    __shared__ unsigned pbuf[CAPB];       // 144 KB (158 KB total; 196 blocks -> 1/CU)
    const int k = blockIdx.x;
    const int t = threadIdx.x;
    const int w = t >> 6, lane = t & 63;  // 16 waves
    bh[t] = 0;
    // preload run bounds for this bucket (column k of histT)
    for (int j = t; j < NBLKA; j += 1024) {
        const int* hrow = histT + (size_t)j * HTS + k;
        hb[j] = make_int2(hrow[0], hrow[1]);
    }
    __syncthreads();
    // pass 1: 1024-bin histogram, 4 runs in flight per wave
    for (int b = w; b < NBLKA; b += 16 * 4) {
        int2 es[4]; unsigned ps[4];
#pragma unroll
        for (int u = 0; u < 4; ++u) {
            int bb = b + 16 * u;
            int2 e = (bb < NBLKA) ? hb[bb] : make_int2(0, 0);
            es[u] = e;
            int j = e.x + lane;
            ps[u] = (j < e.y)
                ? __builtin_nontemporal_load(bucketed + (size_t)bb * EPB + j)
                : 0u;
        }
#pragma unroll
        for (int u = 0; u < 4; ++u) {
            int bb = b + 16 * u;
            if (bb >= NBLKA) break;
            int j = es[u].x + lane;
            if (j < es[u].y) atomicAdd(&bh[(ps[u] >> 18) & 1023], 1);
            for (j += 64; j < es[u].y; j += 64) {   // rare (run > 64)
                unsigned p = __builtin_nontemporal_load(
                    bucketed + (size_t)bb * EPB + j);
                atomicAdd(&bh[(p >> 18) & 1023], 1);
            }
        }
    }
    __syncthreads();
    // exclusive scan of the 1024 bins (in place)
    int v = bh[t];
    for (int off = 1; off < 1024; off <<= 1) {
        int u = (t >= off) ? bh[t - off] : 0;
        __syncthreads();
        bh[t] += u;
        __syncthreads();
    }
    const int base_k = cbase[k];
    const int nseg_b = cbase[k + 1] - base_k;
    int ex = bh[t] - v;                   // exclusive, bucket-relative
    const int node = (k << 10) + t;
    if (node < Nn) row_ptr[node] = base_k + ex;
    bh[t] = ex;                           // own-slot overwrite -> cursor
    __syncthreads();
    const bool fit = (nseg_b <= CAPB);
    if (fit) {
        // pass 2: scatter into LDS pbuf, 4 runs in flight per wave
        for (int b = w; b < NBLKA; b += 16 * 4) {
            int2 es[4]; unsigned ps[4];
#pragma unroll
            for (int u = 0; u < 4; ++u) {
                int bb = b + 16 * u;
                int2 e = (bb < NBLKA) ? hb[bb] : make_int2(0, 0);
                es[u] = e;
                int j = e.x + lane;
                ps[u] = (j < e.y)
                    ? __builtin_nontemporal_load(bucketed + (size_t)bb * EPB + j)
                    : 0u;
            }
#pragma unroll
            for (int u = 0; u < 4; ++u) {
                int bb = b + 16 * u;
                if (bb >= NBLKA) break;
                int j = es[u].x + lane;
                if (j < es[u].y) {
                    unsigned p = ps[u];
                    int pos = atomicAdd(&bh[(p >> 18) & 1023], 1);
                    pbuf[pos] = p & 0x3FFFFu;
                }
                for (j += 64; j < es[u].y; j += 64) {   // rare (run > 64)
                    unsigned p = __builtin_nontemporal_load(
                        bucketed + (size_t)bb * EPB + j);
                    int pos = atomicAdd(&bh[(p >> 18) & 1023], 1);
                    pbuf[pos] = p & 0x3FFFFu;
                }
            }
        }
        __syncthreads();
        // fully-coalesced drain
        for (int j = t; j < nseg_b; j += 1024)
            csr_src[base_k + j] = (int)pbuf[j];
    } else {
        // fallback: direct global scatter (correct, slower; statistically never)
        for (int b = w; b < NBLKA; b += 16) {
            int2 e = hb[b];
            int rb = b * EPB;
            for (int j = e.x + lane; j < e.y; j += 64) {
                unsigned p = bucketed[rb + j];
                int pos = base_k + atomicAdd(&bh[(p >> 18) & 1023], 1);
                csr_src[pos] = (int)(p & 0x3FFFFu);
            }
        }
    }
}

// ============ per-layer kernels ============

// R6: ONE 32B packed record per node (replaces A/Bh/D split arrays):
//   P[i] @ i*32: [0..15] h0..h7 as 4x half2, [16..19] h8 fp32,
//                [20..23] alpha_d fp32, [24..31] pad.
// Per edge, the two loads (dwordx4 @+0, dword @+16) hit the SAME 64B line
// -> MSHR merges them into ONE L2 request (R5 counters showed the agg is
// outstanding-miss bound: 22 waves/CU with 4 loads in flight, yet only
// 6.9% HBM, 24% VALU -> per-CU miss-queue is the wall; halve the requests).
// Table = 6.4 MB (L2+L3 resident). alpha_s recomputed per edge.
// jk is LAYER-MAJOR [L][Nn][9]: contiguous 36B writes per node.
__global__ __launch_bounds__(256) void k_transform(
    const float* __restrict__ xin, int xstride,
    const float* __restrict__ Wl,
    const float* __restrict__ adst,
    char* __restrict__ P)
{
    int i = blockIdx.x * blockDim.x + threadIdx.x;
    if (i >= Nn) return;
    const float* xp = xin + (size_t)i * xstride;
    float xi[Hh];
#pragma unroll
    for (int k = 0; k < Hh; ++k) xi[k] = xp[k];
    float hv[Hh];
#pragma unroll
    for (int j = 0; j < Hh; ++j) {
        float s = 0.f;
#pragma unroll
        for (int k = 0; k < Hh; ++k) s += xi[k] * Wl[k * Hh + j];
        hv[j] = s;
    }
    float ad = 0.f;
#pragma unroll
    for (int j = 0; j < Hh; ++j) ad += hv[j] * adst[j];
    H2F u01, u23, u45, u67;
    u01.h = __floats2half2_rn(hv[0], hv[1]);
    u23.h = __floats2half2_rn(hv[2], hv[3]);
    u45.h = __floats2half2_rn(hv[4], hv[5]);
    u67.h = __floats2half2_rn(hv[6], hv[7]);
    char* rp = P + ((size_t)i << 5);
    *(float4*)rp        = make_float4(u01.f, u23.f, u45.f, u67.f);
    *(float2*)(rp + 16) = make_float2(hv[8], ad);
}

// Per-edge math, shared by both agg paths. x8 is fp32 in the record.
#define AGG_EDGE(F, X8)                                                     \
    {                                                                       \
        H2F u; float2 p;                                                    \
        u.f = (F).x; p = __half22float2(u.h); float x0 = p.x, x1 = p.y;     \
        u.f = (F).y; p = __half22float2(u.h); float x2 = p.x, x3 = p.y;     \
        u.f = (F).z; p = __half22float2(u.h); float x4 = p.x, x5 = p.y;     \
        u.f = (F).w; p = __half22float2(u.h); float x6 = p.x, x7 = p.y;     \
        float x8 = (X8);                                                    \
        float as = x0*s0 + x1*s1 + x2*s2 + x3*s3 + x4*s4                    \
                 + x5*s5 + x6*s6 + x7*s7 + x8*s8;                           \
        float lg = as + c;                                                  \
        lg = lg > 0.f ? lg : 0.2f * lg;                                     \
        float wgt = __expf(lg);                                             \
        a0 += wgt*x0; a1 += wgt*x1; a2 += wgt*x2; a3 += wgt*x3;             \
        a4 += wgt*x4; a5 += wgt*x5; a6 += wgt*x6; a7 += wgt*x7;             \
        a8 += wgt*x8; den += wgt;                                           \
    }

// Oct-per-node gather with LDS-staged CSR; two 2-deep pipelines per lane
// (4 edges in flight). Single-pass softmax: |logits| << 88 so exp never
// overflows; ratio exact.
__global__ __launch_bounds__(256) void k_node_agg(
    const int* __restrict__ rp, const int* __restrict__ csr,
    const char* __restrict__ P, const float* __restrict__ asrc,
    const float* __restrict__ biasl,
    float* __restrict__ jk, int l)
{
    __shared__ int scsr[CAP];
    __shared__ int srp[NPB + 1];
    const int nbase = blockIdx.x * NPB;
    const int t = threadIdx.x;
    if (t <= NPB) srp[t] = rp[nbase + t];   // nbase+NPB <= Nn; rp[Nn] = EP
    __syncthreads();
    const int beg_blk = srp[0];
    const int nseg = srp[NPB] - beg_blk;
    const bool use_lds = (nseg <= CAP);
    if (use_lds)
        for (int j = t; j < nseg; j += 256)
            scsr[j] = __builtin_nontemporal_load(csr + beg_blk + j); // streamed
    __syncthreads();

    // att_src for this layer (uniform -> SGPRs)
    const float s0 = asrc[0], s1 = asrc[1], s2 = asrc[2], s3 = asrc[3],
                s4 = asrc[4], s5 = asrc[5], s6 = asrc[6], s7 = asrc[7],
                s8 = asrc[8];

    const int ni = t >> 3;          // node within block
    const int q  = t & 7;           // lane within oct
    const int i  = nbase + ni;
    const float c = *(const float*)(P + ((size_t)i << 5) + 20); // own alpha_d
    float a0=0,a1=0,a2=0,a3=0,a4=0,a5=0,a6=0,a7=0,a8=0,den=0;
    if (use_lds) {
        const int iend = srp[ni + 1] - beg_blk;
        int i0 = srp[ni] - beg_blk + q;
        int i1 = i0 + 8;
        int sv0 = (i0 < iend) ? scsr[i0] : 0;   // s=0 fallback: valid addr
        int sv1 = (i1 < iend) ? scsr[i1] : 0;
        const char* r0 = P + ((size_t)sv0 << 5);
        const char* r1 = P + ((size_t)sv1 << 5);
        float4 F0 = *(const float4*)r0; float e0 = *(const float*)(r0 + 16);
        float4 F1 = *(const float4*)r1; float e1 = *(const float*)(r1 + 16);
        while (i0 < iend) {
            int n0 = i0 + 16, n1 = i1 + 16;
            int sn0 = (n0 < iend) ? scsr[n0] : 0;
            int sn1 = (n1 < iend) ? scsr[n1] : 0;
            const char* rn0 = P + ((size_t)sn0 << 5);
            const char* rn1 = P + ((size_t)sn1 << 5);
            float4 Fn0 = *(const float4*)rn0;       // issue next gathers
            float en0 = *(const float*)(rn0 + 16);  // (same line: MSHR-merged)
            float4 Fn1 = *(const float4*)rn1;
            float en1 = *(const float*)(rn1 + 16);
            AGG_EDGE(F0, e0);
            if (i1 < iend) AGG_EDGE(F1, e1);
            F0 = Fn0; e0 = en0; F1 = Fn1; e1 = en1;
            i0 = n0; i1 = n1;
        }
    } else {
        for (int e = srp[ni] + q; e < srp[ni + 1]; e += 8) {
            int s = csr[e];
            const char* r0 = P + ((size_t)s << 5);
            float4 F = *(const float4*)r0;
            float e8 = *(const float*)(r0 + 16);
            AGG_EDGE(F, e8);
        }
    }
#pragma unroll
    for (int m = 1; m <= 4; m <<= 1) {
        a0 += __shfl_xor(a0, m); a1 += __shfl_xor(a1, m);
        a2 += __shfl_xor(a2, m); a3 += __shfl_xor(a3, m);
        a4 += __shfl_xor(a4, m); a5 += __shfl_xor(a5, m);
        a6 += __shfl_xor(a6, m); a7 += __shfl_xor(a7, m);
        a8 += __shfl_xor(a8, m); den += __shfl_xor(den, m);
    }
    if (q == 0) {
        float inv = 1.f / den;          // den >= 1 (self-loop term)
        // layer-major jk: contiguous 36B per node -> coalesced, L2-merged
        float* jp = jk + (size_t)l * Nn * Hh + (size_t)i * Hh;
        jp[0] = fmaxf(a0*inv + biasl[0], 0.f);
        jp[1] = fmaxf(a1*inv + biasl[1], 0.f);
        jp[2] = fmaxf(a2*inv + biasl[2], 0.f);
        jp[3] = fmaxf(a3*inv + biasl[3], 0.f);
        jp[4] = fmaxf(a4*inv + biasl[4], 0.f);
        jp[5] = fmaxf(a5*inv + biasl[5], 0.f);
        jp[6] = fmaxf(a6*inv + biasl[6], 0.f);
        jp[7] = fmaxf(a7*inv + biasl[7], 0.f);
        jp[8] = fmaxf(a8*inv + biasl[8], 0.f);
    }
}

// ============ pool + fc ============

// batch is sorted -> graphs are contiguous node ranges. Build range starts.
__global__ __launch_bounds__(256) void k_graph_ptr(
    const int* __restrict__ batch, int* __restrict__ gp)
{
    int i = blockIdx.x * 256 + threadIdx.x;
    if (i >= Nn) return;
    int b = batch[i];
    if (i == 0) {
        for (int g = 0; g <= b; ++g) gp[g] = 0;
    } else {
        int pb = batch[i - 1];
        for (int g = pb + 1; g <= b; ++g) gp[g] = i;
    }
    if (i == Nn - 1) {
        for (int g = b + 1; g <= Gg; ++g) gp[g] = Nn;
    }
}

// Segmented max, one thread per (graph, col). jk is layer-major [L][Nn][9];
// pooled keeps concat order col = l*9+c. Post-relu values >= 0 and init 0
// reproduces the isfinite->0 guard for empty graphs.
__global__ __launch_bounds__(256) void k_pool_seg(
    const float* __restrict__ jk, const int* __restrict__ gp,
    float* __restrict__ pooled)
{
    int t = blockIdx.x * 256 + threadIdx.x;
    if (t >= Gg * JK) return;
    int g = t / JK, col = t - g * JK;
    int lc = col / Hh, cc = col - lc * Hh;
    const float* bp = jk + (size_t)lc * Nn * Hh + cc;
    int beg = gp[g], end = gp[g + 1];
    float m = 0.f;
    for (int i = beg; i < end; ++i)
        m = fmaxf(m, bp[(size_t)i * Hh]);
    pooled[t] = m;
}

__global__ __launch_bounds__(256) void k_fc(
    const float* __restrict__ pooled, const float* __restrict__ fcw,
    const float* __restrict__ fcb, float* __restrict__ out)
{
    int t = blockIdx.x * blockDim.x + threadIdx.x;
    if (t >= Gg * Cc) return;
    int g = t / Cc, c = t - g * Cc;
    float s = fcb[c];
    const float* pp = pooled + (size_t)g * JK;
#pragma unroll
    for (int j = 0; j < JK; ++j) s += pp[j] * fcw[j * Cc + c];
    out[t] = s;
}

extern "C" void kernel_launch(void* const* d_in, const int* in_sizes, int n_in,
                              void* d_out, int out_size, void* d_ws, size_t ws_size,
                              hipStream_t stream) {
    const float* x      = (const float*)d_in[0];   // [N,9]
    const int*   ei     = (const int*)d_in[1];     // [2,E]: src row then dst row
    const int*   batch  = (const int*)d_in[2];     // [N] sorted
    const float* W      = (const float*)d_in[3];   // [L,9,9]
    const float* a_src  = (const float*)d_in[4];   // [L,9]
    const float* a_dst  = (const float*)d_in[5];   // [L,9]
    const float* bias   = (const float*)d_in[6];   // [L,9]
    const float* fc_w   = (const float*)d_in[7];   // [36,2]
    const float* fc_b   = (const float*)d_in[8];   // [2]
    float* out = (float*)d_out;

    // Workspace layout (~64 MB live). histT aliases P, bucketed aliases jk —
    // both dead before P/jk are first written (same-stream ordering).
    char* P          = (char*)d_ws;                       // Nn*32B (6.4MB)
    float* jk        = (float*)(P + ((size_t)Nn << 5));   // Nn*JK (28.8MB), layer-major
    float* pooled    = jk + (size_t)Nn * JK;              // Gg*JK
    int* row_ptr     = (int*)(pooled + (size_t)Gg * JK);  // Nn+1
    int* gp          = row_ptr + Nn + 1;                  // Gg+1
    int* ctot        = gp + Gg + 1;                       // NCB
    int* cbase       = ctot + NCB;                        // NCB+1
    int* csr_src     = cbase + NCB + 1;                   // EP (26.4MB)
    int* histT       = (int*)P;                           // aliases P (0.64MB)
    unsigned* bucketed = (unsigned*)jk;                   // EP alias (26.4MB)

    const int* srcp = ei;
    const int* dstp = ei + Ee;

    // CSR build (edge structure is layer-invariant)
    hipMemsetAsync(ctot, 0, NCB * sizeof(int), stream);
    kA_scatter<<<NBLKA, 256, 0, stream>>>(srcp, dstp, ctot, histT, bucketed);
    k_scan    <<<1, 256, 0, stream>>>(ctot, cbase, row_ptr);
    kB_csr    <<<NCB, 1024, 0, stream>>>(bucketed, histT, cbase, row_ptr, csr_src);

    for (int l = 0; l < Ll; ++l) {
        const float* xin = (l == 0) ? x : (jk + (size_t)(l - 1) * Nn * Hh);
        k_transform<<<NB, 256, 0, stream>>>(xin, Hh, W + l * Hh * Hh,
                                            a_dst + l * Hh, P);
        k_node_agg<<<NAB, 256, 0, stream>>>(row_ptr, csr_src, P,
                                            a_src + l * Hh, bias + l * Hh, jk, l);
    }
    k_graph_ptr<<<NB, 256, 0, stream>>>(batch, gp);
    k_pool_seg<<<(Gg * JK + 255) / 256, 256, 0, stream>>>(jk, gp, pooled);
    k_fc<<<(Gg * Cc + 255) / 256, 256, 0, stream>>>(pooled, fc_w, fc_b, out);
}

// Round 7
// 497.602 us; speedup vs baseline: 1.4781x; 1.0263x over previous
//
#include <hip/hip_runtime.h>
#include <hip/hip_fp16.h>

// Problem constants (from reference)
#define Nn 200000
#define Ee 6400000
#define EP 6600000            // Ee + Nn self loops
#define Hh 9
#define Ll 4
#define Gg 2000
#define Cc 2
#define JK 36                 // Ll * Hh
#define NCB ((Nn + 1023) >> 10) // 196 coarse buckets (1024 nodes each)
#define EPB 8192              // edges per phase-A block
#define NBLKA ((EP + EPB - 1) / EPB) // 806
#define NB ((Nn + 255) / 256) // 782
#define NPB 32                // nodes per k_node_agg block (oct per node)
#define NAB (Nn / NPB)        // 6250 blocks
#define CAP 3072              // staged csr entries per block (12 KB)
#define CAPB 36864            // kB_csr staged entries (144 KB; mean 33792 + 17 sigma)
#define HTS (NCB + 1)         // histT row stride
#define HALF_N (Nn / 2)       // src-half split for gather locality (R7)

union H2F { __half2 h; float f; };

// ========= CSR build: block-major multisplit + per-bucket LDS sort =========

// Phase A: per-block LDS multisplit, drained BLOCK-MAJOR (straight coalesced
// copy). Per-block bucket offsets -> histT row; global bucket totals -> ctot.
// Payload: src (18b) | dst low 10 bits << 18 | src-half bit << 28 (R7: lets
// kB order each dst run by src half -> agg gathers get L2 temporal locality).
__global__ __launch_bounds__(256) void kA_scatter(
    const int* __restrict__ src, const int* __restrict__ dst,
    int* __restrict__ ctot, int* __restrict__ histT,
    unsigned* __restrict__ bucketed)
{
    __shared__ unsigned pbuf[EPB];        // 32 KB
    __shared__ int lh[NCB];
    __shared__ int s[256];
    int t = threadIdx.x;
    if (t < NCB) lh[t] = 0;
    __syncthreads();
    const int base = blockIdx.x * EPB;
    const int nseg = min(EPB, EP - base);
    // pass 1: coarse histogram (dst only)
    for (int j = t; j < nseg; j += 256) {
        int e = base + j;
        int d = (e < Ee) ? dst[e] : (e - Ee);
        atomicAdd(&lh[d >> 10], 1);
    }
    __syncthreads();
    // exclusive scan of 196 bins
    int v = (t < NCB) ? lh[t] : 0;
    s[t] = v; __syncthreads();
    for (int off = 1; off < 256; off <<= 1) {
        int u = (t >= off) ? s[t - off] : 0;
        __syncthreads();
        s[t] += u;
        __syncthreads();
    }
    int* hrow = histT + (size_t)blockIdx.x * HTS;
    if (t < NCB) {
        int ex = s[t] - v;
        lh[t] = ex;                        // LDS cursor
        hrow[t] = ex;                      // run starts for kB
        if (v) atomicAdd(&ctot[t], v);
    }
    if (t == 0) hrow[NCB] = nseg;
    __syncthreads();
    // pass 2: scatter into LDS (bucket-ordered within block)
    for (int j = t; j < nseg; j += 256) {
        int e = base + j;
        int sv, d;
        if (e < Ee) { sv = src[e]; d = dst[e]; } else { sv = e - Ee; d = sv; }
        int pos = atomicAdd(&lh[d >> 10], 1);
        unsigned p = (unsigned)sv | ((unsigned)(d & 1023) << 18);
        if (sv >= HALF_N) p |= (1u << 28);
        pbuf[pos] = p;
    }
    __syncthreads();
    // pass 3: straight coalesced drain, block-major
    for (int j = t; j < nseg; j += 256)
        bucketed[base + j] = pbuf[j];
}

// Scan coarse totals -> cbase.
__global__ __launch_bounds__(256) void k_scan(
    const int* __restrict__ ctot, int* __restrict__ cbase,
    int* __restrict__ row_ptr)
{
    __shared__ int s[256];
    int t = threadIdx.x;
    int v = (t < NCB) ? ctot[t] : 0;
    s[t] = v; __syncthreads();
    for (int off = 1; off < 256; off <<= 1) {
        int u = (t >= off) ? s[t - off] : 0;
        __syncthreads();
        s[t] += u;
        __syncthreads();
    }
    if (t < NCB) cbase[t] = s[t] - v;
    if (t == 0) { cbase[NCB] = EP; row_ptr[Nn] = EP; }
}

// Phase B: ONE 1024-thread block per coarse bucket. R7: 2048 fine bins
// (dst_low << 1 | src_half) so each dst run lists half-0 srcs before half-1
// srcs -> agg's gather stream is temporally local (3.2 MB hot half fits
// per-XCD L2). Barrier-free wave-shfl scan (LDS budget: 6.45+8+144=158.4KB).
__global__ __launch_bounds__(1024) void kB_csr(
    const unsigned* __restrict__ bucketed, const int* __restrict__ histT,
    const int* __restrict__ cbase, int* __restrict__ row_ptr,
    int* __restrict__ csr_src)
{
    __shared__ int2 hb[NBLKA];            // 6.45 KB run bounds
    __shared__ int bh[2048];              // 8 KB: hist -> cursors
    __shared__ unsigned pbuf[CAPB];       // 144 KB
    __shared__ int wsum[16];
    const int k = blockIdx.x;
    const int t = threadIdx.x;
    const int w = t >> 6, lane = t & 63;  // 16 waves
    bh[t] = 0; bh[t + 1024] = 0;
    // preload run bounds for this bucket (column k of histT)
    for (int j = t; j < NBLKA; j += 1024) {
        const int* hrow = histT + (size_t)j * HTS + k;
        hb[j] = make_int2(hrow[0], hrow[1]);
    }
    __syncthreads();
    // pass 1: 2048-bin histogram, 4 runs in flight per wave
    for (int b = w; b < NBLKA; b += 16 * 4) {
        int2 es[4]; unsigned ps[4];
#pragma unroll
        for (int u = 0; u < 4; ++u) {
            int bb = b + 16 * u;
            int2 e = (bb < NBLKA) ? hb[bb] : make_int2(0, 0);
            es[u] = e;
            int j = e.x + lane;
            ps[u] = (j < e.y)
                ? __builtin_nontemporal_load(bucketed + (size_t)bb * EPB + j)
                : 0u;
        }
#pragma unroll
        for (int u = 0; u < 4; ++u) {
            int bb = b + 16 * u;
            if (bb >= NBLKA) break;
            int j = es[u].x + lane;
            if (j < es[u].y) {
                unsigned p = ps[u];
                atomicAdd(&bh[(((p >> 18) & 1023) << 1) | ((p >> 28) & 1)], 1);
            }
            for (j += 64; j < es[u].y; j += 64) {   // rare (run > 64)
                unsigned p = __builtin_nontemporal_load(
                    bucketed + (size_t)bb * EPB + j);
                atomicAdd(&bh[(((p >> 18) & 1023) << 1) | ((p >> 28) & 1)], 1);
            }
        }
    }
    __syncthreads();
    // exclusive scan of 2048 bins: per-thread pair + wave shfl scan + bases
    int v0 = bh[2 * t], v1 = bh[2 * t + 1];
    int sum = v0 + v1;
    int incl = sum;
#pragma unroll
    for (int off = 1; off < 64; off <<= 1) {
        int u = __shfl_up(incl, off);
        if (lane >= off) incl += u;
    }
    if (lane == 63) wsum[w] = incl;
    __syncthreads();
    if (t == 0) {
        int acc = 0;
#pragma unroll
        for (int i2 = 0; i2 < 16; ++i2) { int x = wsum[i2]; wsum[i2] = acc; acc += x; }
    }
    __syncthreads();
    int excl = wsum[w] + incl - sum;      // exclusive prefix of bin 2t
    const int base_k = cbase[k];
    const int nseg_b = cbase[k + 1] - base_k;
    const int node = (k << 10) + t;
    if (node < Nn) row_ptr[node] = base_k + excl;  // dst run start = bin 2t
    bh[2 * t] = excl;                     // cursors (own slots only)
    bh[2 * t + 1] = excl + v0;
    __syncthreads();
    const bool fit = (nseg_b <= CAPB);
    if (fit) {
        // pass 2: scatter into LDS pbuf, 4 runs in flight per wave
        for (int b = w; b < NBLKA; b += 16 * 4) {
            int2 es[4]; unsigned ps[4];
#pragma unroll
            for (int u = 0; u < 4; ++u) {
                int bb = b + 16 * u;
                int2 e = (bb < NBLKA) ? hb[bb] : make_int2(0, 0);
                es[u] = e;
                int j = e.x + lane;
                ps[u] = (j < e.y)
                    ? __builtin_nontemporal_load(bucketed + (size_t)bb * EPB + j)
                    : 0u;
            }
#pragma unroll
            for (int u = 0; u < 4; ++u) {
                int bb = b + 16 * u;
                if (bb >= NBLKA) break;
                int j = es[u].x + lane;
                if (j < es[u].y) {
                    unsigned p = ps[u];
                    int pos = atomicAdd(
                        &bh[(((p >> 18) & 1023) << 1) | ((p >> 28) & 1)], 1);
                    pbuf[pos] = p & 0x3FFFFu;
                }
                for (j += 64; j < es[u].y; j += 64) {   // rare (run > 64)
                    unsigned p = __builtin_nontemporal_load(
                        bucketed + (size_t)bb * EPB + j);
                    int pos = atomicAdd(
                        &bh[(((p >> 18) & 1023) << 1) | ((p >> 28) & 1)], 1);
                    pbuf[pos] = p & 0x3FFFFu;
                }
            }
        }
        __syncthreads();
        // fully-coalesced drain
        for (int j = t; j < nseg_b; j += 1024)
            csr_src[base_k + j] = (int)pbuf[j];
    } else {
        // fallback: direct global scatter (correct, slower; statistically never)
        for (int b = w; b < NBLKA; b += 16) {
            int2 e = hb[b];
            int rb = b * EPB;
            for (int j = e.x + lane; j < e.y; j += 64) {
                unsigned p = bucketed[rb + j];
                int pos = base_k + atomicAdd(
                    &bh[(((p >> 18) & 1023) << 1) | ((p >> 28) & 1)], 1);
                csr_src[pos] = (int)(p & 0x3FFFFu);
            }
        }
    }
}

// ============ per-layer kernels ============

// ONE 32B packed record per node:
//   P[i] @ i*32: [0..15] h0..h7 as 4x half2, [16..19] h8 fp32,
//                [20..23] alpha_d fp32, [24..31] pad.
// Per edge, both loads hit the SAME 64B line -> one L2 request (R6).
// R7: csr runs are src-half ordered, so the hot table half (3.2 MB) stays
// per-XCD L2 resident. alpha_s recomputed per edge.
// jk is LAYER-MAJOR [L][Nn][9]: contiguous 36B writes per node.
__global__ __launch_bounds__(256) void k_transform(
    const float* __restrict__ xin, int xstride,
    const float* __restrict__ Wl,
    const float* __restrict__ adst,
    char* __restrict__ P)
{
    int i = blockIdx.x * blockDim.x + threadIdx.x;
    if (i >= Nn) return;
    const float* xp = xin + (size_t)i * xstride;
    float xi[Hh];
#pragma unroll
    for (int k = 0; k < Hh; ++k) xi[k] = xp[k];
    float hv[Hh];
#pragma unroll
    for (int j = 0; j < Hh; ++j) {
        float s = 0.f;
#pragma unroll
        for (int k = 0; k < Hh; ++k) s += xi[k] * Wl[k * Hh + j];
        hv[j] = s;
    }
    float ad = 0.f;
#pragma unroll
    for (int j = 0; j < Hh; ++j) ad += hv[j] * adst[j];
    H2F u01, u23, u45, u67;
    u01.h = __floats2half2_rn(hv[0], hv[1]);
    u23.h = __floats2half2_rn(hv[2], hv[3]);
    u45.h = __floats2half2_rn(hv[4], hv[5]);
    u67.h = __floats2half2_rn(hv[6], hv[7]);
    char* rp = P + ((size_t)i << 5);
    *(float4*)rp        = make_float4(u01.f, u23.f, u45.f, u67.f);
    *(float2*)(rp + 16) = make_float2(hv[8], ad);
}

// Per-edge math, shared by both agg paths. x8 is fp32 in the record.
#define AGG_EDGE(F, X8)                                                     \
    {                                                                       \
        H2F u; float2 p;                                                    \
        u.f = (F).x; p = __half22float2(u.h); float x0 = p.x, x1 = p.y;     \
        u.f = (F).y; p = __half22float2(u.h); float x2 = p.x, x3 = p.y;     \
        u.f = (F).z; p = __half22float2(u.h); float x4 = p.x, x5 = p.y;     \
        u.f = (F).w; p = __half22float2(u.h); float x6 = p.x, x7 = p.y;     \
        float x8 = (X8);                                                    \
        float as = x0*s0 + x1*s1 + x2*s2 + x3*s3 + x4*s4                    \
                 + x5*s5 + x6*s6 + x7*s7 + x8*s8;                           \
        float lg = as + c;                                                  \
        lg = lg > 0.f ? lg : 0.2f * lg;                                     \
        float wgt = __expf(lg);                                             \
        a0 += wgt*x0; a1 += wgt*x1; a2 += wgt*x2; a3 += wgt*x3;             \
        a4 += wgt*x4; a5 += wgt*x5; a6 += wgt*x6; a7 += wgt*x7;             \
        a8 += wgt*x8; den += wgt;                                           \
    }

// Oct-per-node gather with LDS-staged CSR; two 2-deep pipelines per lane
// (4 edges in flight). Single-pass softmax: |logits| << 88 so exp never
// overflows; ratio exact. Unchanged in R7 — run ordering does the work.
__global__ __launch_bounds__(256) void k_node_agg(
    const int* __restrict__ rp, const int* __restrict__ csr,
    const char* __restrict__ P, const float* __restrict__ asrc,
    const float* __restrict__ biasl,
    float* __restrict__ jk, int l)
{
    __shared__ int scsr[CAP];
    __shared__ int srp[NPB + 1];
    const int nbase = blockIdx.x * NPB;
    const int t = threadIdx.x;
    if (t <= NPB) srp[t] = rp[nbase + t];   // nbase+NPB <= Nn; rp[Nn] = EP
    __syncthreads();
    const int beg_blk = srp[0];
    const int nseg = srp[NPB] - beg_blk;
    const bool use_lds = (nseg <= CAP);
    if (use_lds)
        for (int j = t; j < nseg; j += 256)
            scsr[j] = __builtin_nontemporal_load(csr + beg_blk + j); // streamed
    __syncthreads();

    // att_src for this layer (uniform -> SGPRs)
    const float s0 = asrc[0], s1 = asrc[1], s2 = asrc[2], s3 = asrc[3],
                s4 = asrc[4], s5 = asrc[5], s6 = asrc[6], s7 = asrc[7],
                s8 = asrc[8];

    const int ni = t >> 3;          // node within block
    const int q  = t & 7;           // lane within oct
    const int i  = nbase + ni;
    const float c = *(const float*)(P + ((size_t)i << 5) + 20); // own alpha_d
    float a0=0,a1=0,a2=0,a3=0,a4=0,a5=0,a6=0,a7=0,a8=0,den=0;
    if (use_lds) {
        const int iend = srp[ni + 1] - beg_blk;
        int i0 = srp[ni] - beg_blk + q;
        int i1 = i0 + 8;
        int sv0 = (i0 < iend) ? scsr[i0] : 0;   // s=0 fallback: valid addr
        int sv1 = (i1 < iend) ? scsr[i1] : 0;
        const char* r0 = P + ((size_t)sv0 << 5);
        const char* r1 = P + ((size_t)sv1 << 5);
        float4 F0 = *(const float4*)r0; float e0 = *(const float*)(r0 + 16);
        float4 F1 = *(const float4*)r1; float e1 = *(const float*)(r1 + 16);
        while (i0 < iend) {
            int n0 = i0 + 16, n1 = i1 + 16;
            int sn0 = (n0 < iend) ? scsr[n0] : 0;
            int sn1 = (n1 < iend) ? scsr[n1] : 0;
            const char* rn0 = P + ((size_t)sn0 << 5);
            const char* rn1 = P + ((size_t)sn1 << 5);
            float4 Fn0 = *(const float4*)rn0;       // issue next gathers
            float en0 = *(const float*)(rn0 + 16);  // (same line: MSHR-merged)
            float4 Fn1 = *(const float4*)rn1;
            float en1 = *(const float*)(rn1 + 16);
            AGG_EDGE(F0, e0);
            if (i1 < iend) AGG_EDGE(F1, e1);
            F0 = Fn0; e0 = en0; F1 = Fn1; e1 = en1;
            i0 = n0; i1 = n1;
        }
    } else {
        for (int e = srp[ni] + q; e < srp[ni + 1]; e += 8) {
            int s = csr[e];
            const char* r0 = P + ((size_t)s << 5);
            float4 F = *(const float4*)r0;
            float e8 = *(const float*)(r0 + 16);
            AGG_EDGE(F, e8);
        }
    }
#pragma unroll
    for (int m = 1; m <= 4; m <<= 1) {
        a0 += __shfl_xor(a0, m); a1 += __shfl_xor(a1, m);
        a2 += __shfl_xor(a2, m); a3 += __shfl_xor(a3, m);
        a4 += __shfl_xor(a4, m); a5 += __shfl_xor(a5, m);
        a6 += __shfl_xor(a6, m); a7 += __shfl_xor(a7, m);
        a8 += __shfl_xor(a8, m); den += __shfl_xor(den, m);
    }
    if (q == 0) {
        float inv = 1.f / den;          // den >= 1 (self-loop term)
        // layer-major jk: contiguous 36B per node -> coalesced, L2-merged
        float* jp = jk + (size_t)l * Nn * Hh + (size_t)i * Hh;
        jp[0] = fmaxf(a0*inv + biasl[0], 0.f);
        jp[1] = fmaxf(a1*inv + biasl[1], 0.f);
        jp[2] = fmaxf(a2*inv + biasl[2], 0.f);
        jp[3] = fmaxf(a3*inv + biasl[3], 0.f);
        jp[4] = fmaxf(a4*inv + biasl[4], 0.f);
        jp[5] = fmaxf(a5*inv + biasl[5], 0.f);
        jp[6] = fmaxf(a6*inv + biasl[6], 0.f);
        jp[7] = fmaxf(a7*inv + biasl[7], 0.f);
        jp[8] = fmaxf(a8*inv + biasl[8], 0.f);
    }
}

// ============ pool + fc ============

// batch is sorted -> graphs are contiguous node ranges. Build range starts.
__global__ __launch_bounds__(256) void k_graph_ptr(
    const int* __restrict__ batch, int* __restrict__ gp)
{
    int i = blockIdx.x * 256 + threadIdx.x;
    if (i >= Nn) return;
    int b = batch[i];
    if (i == 0) {
        for (int g = 0; g <= b; ++g) gp[g] = 0;
    } else {
        int pb = batch[i - 1];
        for (int g = pb + 1; g <= b; ++g) gp[g] = i;
    }
    if (i == Nn - 1) {
        for (int g = b + 1; g <= Gg; ++g) gp[g] = Nn;
    }
}

// Segmented max, one thread per (graph, col). jk is layer-major [L][Nn][9];
// pooled keeps concat order col = l*9+c. Post-relu values >= 0 and init 0
// reproduces the isfinite->0 guard for empty graphs.
__global__ __launch_bounds__(256) void k_pool_seg(
    const float* __restrict__ jk, const int* __restrict__ gp,
    float* __restrict__ pooled)
{
    int t = blockIdx.x * 256 + threadIdx.x;
    if (t >= Gg * JK) return;
    int g = t / JK, col = t - g * JK;
    int lc = col / Hh, cc = col - lc * Hh;
    const float* bp = jk + (size_t)lc * Nn * Hh + cc;
    int beg = gp[g], end = gp[g + 1];
    float m = 0.f;
    for (int i = beg; i < end; ++i)
        m = fmaxf(m, bp[(size_t)i * Hh]);
    pooled[t] = m;
}

__global__ __launch_bounds__(256) void k_fc(
    const float* __restrict__ pooled, const float* __restrict__ fcw,
    const float* __restrict__ fcb, float* __restrict__ out)
{
    int t = blockIdx.x * blockDim.x + threadIdx.x;
    if (t >= Gg * Cc) return;
    int g = t / Cc, c = t - g * Cc;
    float s = fcb[c];
    const float* pp = pooled + (size_t)g * JK;
#pragma unroll
    for (int j = 0; j < JK; ++j) s += pp[j] * fcw[j * Cc + c];
    out[t] = s;
}

extern "C" void kernel_launch(void* const* d_in, const int* in_sizes, int n_in,
                              void* d_out, int out_size, void* d_ws, size_t ws_size,
                              hipStream_t stream) {
    const float* x      = (const float*)d_in[0];   // [N,9]
    const int*   ei     = (const int*)d_in[1];     // [2,E]: src row then dst row
    const int*   batch  = (const int*)d_in[2];     // [N] sorted
    const float* W      = (const float*)d_in[3];   // [L,9,9]
    const float* a_src  = (const float*)d_in[4];   // [L,9]
    const float* a_dst  = (const float*)d_in[5];   // [L,9]
    const float* bias   = (const float*)d_in[6];   // [L,9]
    const float* fc_w   = (const float*)d_in[7];   // [36,2]
    const float* fc_b   = (const float*)d_in[8];   // [2]
    float* out = (float*)d_out;

    // Workspace layout (~64 MB live). histT aliases P, bucketed aliases jk —
    // both dead before P/jk are first written (same-stream ordering).
    char* P          = (char*)d_ws;                       // Nn*32B (6.4MB)
    float* jk        = (float*)(P + ((size_t)Nn << 5));   // Nn*JK (28.8MB), layer-major
    float* pooled    = jk + (size_t)Nn * JK;              // Gg*JK
    int* row_ptr     = (int*)(pooled + (size_t)Gg * JK);  // Nn+1
    int* gp          = row_ptr + Nn + 1;                  // Gg+1
    int* ctot        = gp + Gg + 1;                       // NCB
    int* cbase       = ctot + NCB;                        // NCB+1
    int* csr_src     = cbase + NCB + 1;                   // EP (26.4MB)
    int* histT       = (int*)P;                           // aliases P (0.64MB)
    unsigned* bucketed = (unsigned*)jk;                   // EP alias (26.4MB)

    const int* srcp = ei;
    const int* dstp = ei + Ee;

    // CSR build (edge structure is layer-invariant)
    hipMemsetAsync(ctot, 0, NCB * sizeof(int), stream);
    kA_scatter<<<NBLKA, 256, 0, stream>>>(srcp, dstp, ctot, histT, bucketed);
    k_scan    <<<1, 256, 0, stream>>>(ctot, cbase, row_ptr);
    kB_csr    <<<NCB, 1024, 0, stream>>>(bucketed, histT, cbase, row_ptr, csr_src);

    for (int l = 0; l < Ll; ++l) {
        const float* xin = (l == 0) ? x : (jk + (size_t)(l - 1) * Nn * Hh);
        k_transform<<<NB, 256, 0, stream>>>(xin, Hh, W + l * Hh * Hh,
                                            a_dst + l * Hh, P);
        k_node_agg<<<NAB, 256, 0, stream>>>(row_ptr, csr_src, P,
                                            a_src + l * Hh, bias + l * Hh, jk, l);
    }
    k_graph_ptr<<<NB, 256, 0, stream>>>(batch, gp);
    k_pool_seg<<<(Gg * JK + 255) / 256, 256, 0, stream>>>(jk, gp, pooled);
    k_fc<<<(Gg * Cc + 255) / 256, 256, 0, stream>>>(pooled, fc_w, fc_b, out);
}

// Round 8
// 496.932 us; speedup vs baseline: 1.4801x; 1.0013x over previous
//
#include <hip/hip_runtime.h>
#include <hip/hip_fp16.h>

// Problem constants (from reference)
#define Nn 200000
#define Ee 6400000
#define EP 6600000            // Ee + Nn self loops
#define Hh 9
#define Ll 4
#define Gg 2000
#define Cc 2
#define JK 36                 // Ll * Hh
#define NCB ((Nn + 1023) >> 10) // 196 coarse buckets (1024 nodes each)
#define EPB 8192              // edges per phase-A block
#define NBLKA ((EP + EPB - 1) / EPB) // 806
#define NB ((Nn + 255) / 256) // 782
#define NPB 32                // nodes per k_node_agg block (oct per node)
#define NAB (Nn / NPB)        // 6250 blocks
#define CAP 3072              // staged csr entries per block (12 KB)
#define CAPB 36864            // kB_csr staged entries (144 KB)
#define HTS (NCB + 1)         // histT row stride
#define HALF_N 100000         // src-half split: table half = 3.2MB, L2-resident

union H2F { __half2 h; float f; };

// ========= CSR build: block-major multisplit + per-bucket LDS sort =========
// R8: csr_src is TWO dst-ordered arrays: csrA (src<HALF_N) then csrB, with
// separate row pointers rpA/rpB. The agg then runs two dispatch-separated
// passes, each gathering from ONE 3.2MB table half (per-XCD L2 resident) —
// R7 proved per-run ordering can't give phase coherence; dispatches can.

// Phase A: per-block LDS multisplit, drained BLOCK-MAJOR. Per-block bucket
// offsets -> histT row; per-(bucket,half) totals -> ctotH (392 LDS-aggregated
// atomics/block). Payload: src 18b | dst_low10 << 18 | src_half << 28.
__global__ __launch_bounds__(256) void kA_scatter(
    const int* __restrict__ src, const int* __restrict__ dst,
    int* __restrict__ ctotH, int* __restrict__ histT,
    unsigned* __restrict__ bucketed)
{
    __shared__ unsigned pbuf[EPB];        // 32 KB
    __shared__ int lh[NCB];
    __shared__ int lhh[2 * NCB];          // per-(bucket,half) counts
    __shared__ int s[256];
    int t = threadIdx.x;
    if (t < NCB) lh[t] = 0;
    for (int j = t; j < 2 * NCB; j += 256) lhh[j] = 0;
    __syncthreads();
    const int base = blockIdx.x * EPB;
    const int nseg = min(EPB, EP - base);
    // pass 1: coarse histogram (dst only)
    for (int j = t; j < nseg; j += 256) {
        int e = base + j;
        int d = (e < Ee) ? dst[e] : (e - Ee);
        atomicAdd(&lh[d >> 10], 1);
    }
    __syncthreads();
    // exclusive scan of 196 bins
    int v = (t < NCB) ? lh[t] : 0;
    s[t] = v; __syncthreads();
    for (int off = 1; off < 256; off <<= 1) {
        int u = (t >= off) ? s[t - off] : 0;
        __syncthreads();
        s[t] += u;
        __syncthreads();
    }
    int* hrow = histT + (size_t)blockIdx.x * HTS;
    if (t < NCB) {
        int ex = s[t] - v;
        lh[t] = ex;                        // LDS cursor
        hrow[t] = ex;                      // run starts for kB
    }
    if (t == 0) hrow[NCB] = nseg;
    __syncthreads();
    // pass 2: scatter into LDS (bucket-ordered within block) + half counts
    for (int j = t; j < nseg; j += 256) {
        int e = base + j;
        int sv, d;
        if (e < Ee) { sv = src[e]; d = dst[e]; } else { sv = e - Ee; d = sv; }
        int hbit = (sv >= HALF_N) ? 1 : 0;
        int pos = atomicAdd(&lh[d >> 10], 1);
        atomicAdd(&lhh[((d >> 10) << 1) | hbit], 1);
        pbuf[pos] = (unsigned)sv | ((unsigned)(d & 1023) << 18)
                  | ((unsigned)hbit << 28);
    }
    __syncthreads();
    // pass 3: coalesced drain + global per-(bucket,half) totals
    for (int j = t; j < nseg; j += 256)
        bucketed[base + j] = pbuf[j];
    for (int j = t; j < 2 * NCB; j += 256) {
        int c = lhh[j];
        if (c) atomicAdd(&ctotH[(j & 1) * NCB + (j >> 1)], c);  // [half][bucket]
    }
}

// Scan 392 per-(half,bucket) totals -> cbaseH[0..392]. Layout [A0..A195,
// B0..B195] so csrA occupies [0, EA) and csrB [EA, EP) of csr_src.
__global__ __launch_bounds__(512) void k_scan(
    const int* __restrict__ ctotH, int* __restrict__ cbaseH,
    int* __restrict__ rpA, int* __restrict__ rpB)
{
    __shared__ int s[512];
    int t = threadIdx.x;
    int v = (t < 2 * NCB) ? ctotH[t] : 0;
    s[t] = v; __syncthreads();
    for (int off = 1; off < 512; off <<= 1) {
        int u = (t >= off) ? s[t - off] : 0;
        __syncthreads();
        s[t] += u;
        __syncthreads();
    }
    if (t < 2 * NCB) cbaseH[t] = s[t] - v;
    if (t == NCB) rpA[Nn] = s[NCB] - v;       // EA sentinel
    if (t == 0) { cbaseH[2 * NCB] = EP; rpB[Nn] = EP; }
}

// Phase B: ONE 1024-thread block per coarse bucket. 2048 fine bins
// (dst_low<<1 | half); in-bucket layout: ALL half-0 edges (dst-ordered)
// then all half-1 -> drained to csrA / csrB regions. Dual wave-shfl scans.
__global__ __launch_bounds__(1024) void kB_csr(
    const unsigned* __restrict__ bucketed, const int* __restrict__ histT,
    const int* __restrict__ cbaseH, int* __restrict__ rpA,
    int* __restrict__ rpB, int* __restrict__ csr_src)
{
    __shared__ int2 hb[NBLKA];            // 6.45 KB run bounds
    __shared__ int bh[2048];              // 8 KB: hist -> cursors
    __shared__ unsigned pbuf[CAPB];       // 144 KB
    __shared__ int wsumA[16], wsumB[16];
    const int k = blockIdx.x;
    const int t = threadIdx.x;
    const int w = t >> 6, lane = t & 63;  // 16 waves
    bh[t] = 0; bh[t + 1024] = 0;
    for (int j = t; j < NBLKA; j += 1024) {
        const int* hrow = histT + (size_t)j * HTS + k;
        hb[j] = make_int2(hrow[0], hrow[1]);
    }
    __syncthreads();
    // pass 1: 2048-bin histogram, 4 runs in flight per wave
    for (int b = w; b < NBLKA; b += 16 * 4) {
        int2 es[4]; unsigned ps[4];
#pragma unroll
        for (int u = 0; u < 4; ++u) {
            int bb = b + 16 * u;
            int2 e = (bb < NBLKA) ? hb[bb] : make_int2(0, 0);
            es[u] = e;
            int j = e.x + lane;
            ps[u] = (j < e.y)
                ? __builtin_nontemporal_load(bucketed + (size_t)bb * EPB + j)
                : 0u;
        }
#pragma unroll
        for (int u = 0; u < 4; ++u) {
            int bb = b + 16 * u;
            if (bb >= NBLKA) break;
            int j = es[u].x + lane;
            if (j < es[u].y) {
                unsigned p = ps[u];
                atomicAdd(&bh[(((p >> 18) & 1023) << 1) | ((p >> 28) & 1)], 1);
            }
            for (j += 64; j < es[u].y; j += 64) {
                unsigned p = __builtin_nontemporal_load(
                    bucketed + (size_t)bb * EPB + j);
                atomicAdd(&bh[(((p >> 18) & 1023) << 1) | ((p >> 28) & 1)], 1);
            }
        }
    }
    __syncthreads();
    // dual scans: half-0 counts (v0) and half-1 counts (v1) separately
    int v0 = bh[2 * t], v1 = bh[2 * t + 1];
    int iA = v0, iB = v1;
#pragma unroll
    for (int off = 1; off < 64; off <<= 1) {
        int uA = __shfl_up(iA, off);
        int uB = __shfl_up(iB, off);
        if (lane >= off) { iA += uA; iB += uB; }
    }
    if (lane == 63) { wsumA[w] = iA; wsumB[w] = iB; }
    __syncthreads();
    if (t == 0) {
        int acc = 0;
#pragma unroll
        for (int i2 = 0; i2 < 16; ++i2) { int x = wsumA[i2]; wsumA[i2] = acc; acc += x; }
        acc = 0;
#pragma unroll
        for (int i2 = 0; i2 < 16; ++i2) { int x = wsumB[i2]; wsumB[i2] = acc; acc += x; }
    }
    __syncthreads();
    int exA = wsumA[w] + iA - v0;         // in-bucket exclusive, half-0
    int exB = wsumB[w] + iB - v1;         // in-bucket exclusive, half-1
    const int baseA = cbaseH[k];
    const int totA  = cbaseH[k + 1] - baseA;
    const int baseB = cbaseH[NCB + k];
    const int totB  = cbaseH[NCB + k + 1] - baseB;
    const int nseg_b = totA + totB;
    const int node = (k << 10) + t;
    if (node < Nn) { rpA[node] = baseA + exA; rpB[node] = baseB + exB; }
    bh[2 * t] = exA;                      // pbuf-relative cursors
    bh[2 * t + 1] = totA + exB;
    __syncthreads();
    const bool fit = (nseg_b <= CAPB);
    if (fit) {
        // pass 2: scatter into LDS pbuf, 4 runs in flight per wave
        for (int b = w; b < NBLKA; b += 16 * 4) {
            int2 es[4]; unsigned ps[4];
#pragma unroll
            for (int u = 0; u < 4; ++u) {
                int bb = b + 16 * u;
                int2 e = (bb < NBLKA) ? hb[bb] : make_int2(0, 0);
                es[u] = e;
                int j = e.x + lane;
                ps[u] = (j < e.y)
                    ? __builtin_nontemporal_load(bucketed + (size_t)bb * EPB + j)
                    : 0u;
            }
#pragma unroll
            for (int u = 0; u < 4; ++u) {
                int bb = b + 16 * u;
                if (bb >= NBLKA) break;
                int j = es[u].x + lane;
                if (j < es[u].y) {
                    unsigned p = ps[u];
                    int pos = atomicAdd(
                        &bh[(((p >> 18) & 1023) << 1) | ((p >> 28) & 1)], 1);
                    pbuf[pos] = p & 0x3FFFFu;
                }
                for (j += 64; j < es[u].y; j += 64) {
                    unsigned p = __builtin_nontemporal_load(
                        bucketed + (size_t)bb * EPB + j);
                    int pos = atomicAdd(
                        &bh[(((p >> 18) & 1023) << 1) | ((p >> 28) & 1)], 1);
                    pbuf[pos] = p & 0x3FFFFu;
                }
            }
        }
        __syncthreads();
        // coalesced drains into the two csr regions
        for (int j = t; j < totA; j += 1024)
            csr_src[baseA + j] = (int)pbuf[j];
        for (int j = t; j < totB; j += 1024)
            csr_src[baseB + j] = (int)pbuf[totA + j];
    } else {
        // fallback: direct global scatter (statistically never)
        for (int b = w; b < NBLKA; b += 16) {
            int2 e = hb[b];
            int rb = b * EPB;
            for (int j = e.x + lane; j < e.y; j += 64) {
                unsigned p = bucketed[rb + j];
                int pos = atomicAdd(
                    &bh[(((p >> 18) & 1023) << 1) | ((p >> 28) & 1)], 1);
                int abspos = (pos < totA) ? baseA + pos : baseB + (pos - totA);
                csr_src[abspos] = (int)(p & 0x3FFFFu);
            }
        }
    }
}

// ============ per-layer kernels ============

// ONE 32B packed record per node:
//   P[i] @ i*32: [0..15] h0..h7 as 4x half2, [16..19] h8 fp32,
//                [20..23] alpha_d fp32, [24..31] pad.
// Per edge both loads hit the SAME 64B line -> one L2 request. Per pass the
// gather set is ONE half (3.2MB) -> per-XCD L2 resident. jk LAYER-MAJOR.
__global__ __launch_bounds__(256) void k_transform(
    const float* __restrict__ xin, int xstride,
    const float* __restrict__ Wl,
    const float* __restrict__ adst,
    char* __restrict__ P)
{
    int i = blockIdx.x * blockDim.x + threadIdx.x;
    if (i >= Nn) return;
    const float* xp = xin + (size_t)i * xstride;
    float xi[Hh];
#pragma unroll
    for (int k = 0; k < Hh; ++k) xi[k] = xp[k];
    float hv[Hh];
#pragma unroll
    for (int j = 0; j < Hh; ++j) {
        float s = 0.f;
#pragma unroll
        for (int k = 0; k < Hh; ++k) s += xi[k] * Wl[k * Hh + j];
        hv[j] = s;
    }
    float ad = 0.f;
#pragma unroll
    for (int j = 0; j < Hh; ++j) ad += hv[j] * adst[j];
    H2F u01, u23, u45, u67;
    u01.h = __floats2half2_rn(hv[0], hv[1]);
    u23.h = __floats2half2_rn(hv[2], hv[3]);
    u45.h = __floats2half2_rn(hv[4], hv[5]);
    u67.h = __floats2half2_rn(hv[6], hv[7]);
    char* rp = P + ((size_t)i << 5);
    *(float4*)rp        = make_float4(u01.f, u23.f, u45.f, u67.f);
    *(float2*)(rp + 16) = make_float2(hv[8], ad);
}

// Per-edge math. x8 is fp32 in the record.
#define AGG_EDGE(F, X8)                                                     \
    {                                                                       \
        H2F u; float2 p;                                                    \
        u.f = (F).x; p = __half22float2(u.h); float x0 = p.x, x1 = p.y;     \
        u.f = (F).y; p = __half22float2(u.h); float x2 = p.x, x3 = p.y;     \
        u.f = (F).z; p = __half22float2(u.h); float x4 = p.x, x5 = p.y;     \
        u.f = (F).w; p = __half22float2(u.h); float x6 = p.x, x7 = p.y;     \
        float x8 = (X8);                                                    \
        float as = x0*s0 + x1*s1 + x2*s2 + x3*s3 + x4*s4                    \
                 + x5*s5 + x6*s6 + x7*s7 + x8*s8;                           \
        float lg = as + c;                                                  \
        lg = lg > 0.f ? lg : 0.2f * lg;                                     \
        float wgt = __expf(lg);                                             \
        a0 += wgt*x0; a1 += wgt*x1; a2 += wgt*x2; a3 += wgt*x3;             \
        a4 += wgt*x4; a5 += wgt*x5; a6 += wgt*x6; a7 += wgt*x7;             \
        a8 += wgt*x8; den += wgt;                                           \
    }

// Oct-per-node gather, LDS-staged CSR, two 2-deep pipelines (4 in flight).
// mode 0: edges from rp=rpA (src half 0); write RAW sums to jk + den to denP.
// mode 1: edges from rp=rpB (src half 1); add partials, finalize (bias+relu).
// Single-pass softmax (no max subtraction): |logits| << 88, exp safe.
__global__ __launch_bounds__(256) void k_node_agg(
    const int* __restrict__ rp, const int* __restrict__ csr,
    const char* __restrict__ P, const float* __restrict__ asrc,
    const float* __restrict__ biasl,
    float* __restrict__ jk, float* __restrict__ denP, int l, int mode)
{
    __shared__ int scsr[CAP];
    __shared__ int srp[NPB + 1];
    const int nbase = blockIdx.x * NPB;
    const int t = threadIdx.x;
    if (t <= NPB) srp[t] = rp[nbase + t];   // rp has Nn+1 entries (sentinel)
    __syncthreads();
    const int beg_blk = srp[0];
    const int nseg = srp[NPB] - beg_blk;
    const bool use_lds = (nseg <= CAP);
    if (use_lds)
        for (int j = t; j < nseg; j += 256)
            scsr[j] = __builtin_nontemporal_load(csr + beg_blk + j);
    __syncthreads();

    const float s0 = asrc[0], s1 = asrc[1], s2 = asrc[2], s3 = asrc[3],
                s4 = asrc[4], s5 = asrc[5], s6 = asrc[6], s7 = asrc[7],
                s8 = asrc[8];

    const int ni = t >> 3;          // node within block
    const int q  = t & 7;           // lane within oct
    const int i  = nbase + ni;
    const float c = *(const float*)(P + ((size_t)i << 5) + 20); // own alpha_d
    float a0=0,a1=0,a2=0,a3=0,a4=0,a5=0,a6=0,a7=0,a8=0,den=0;
    if (use_lds) {
        const int iend = srp[ni + 1] - beg_blk;
        int i0 = srp[ni] - beg_blk + q;
        int i1 = i0 + 8;
        int sv0 = (i0 < iend) ? scsr[i0] : 0;
        int sv1 = (i1 < iend) ? scsr[i1] : 0;
        const char* r0 = P + ((size_t)sv0 << 5);
        const char* r1 = P + ((size_t)sv1 << 5);
        float4 F0 = *(const float4*)r0; float e0 = *(const float*)(r0 + 16);
        float4 F1 = *(const float4*)r1; float e1 = *(const float*)(r1 + 16);
        while (i0 < iend) {
            int n0 = i0 + 16, n1 = i1 + 16;
            int sn0 = (n0 < iend) ? scsr[n0] : 0;
            int sn1 = (n1 < iend) ? scsr[n1] : 0;
            const char* rn0 = P + ((size_t)sn0 << 5);
            const char* rn1 = P + ((size_t)sn1 << 5);
            float4 Fn0 = *(const float4*)rn0;
            float en0 = *(const float*)(rn0 + 16);
            float4 Fn1 = *(const float4*)rn1;
            float en1 = *(const float*)(rn1 + 16);
            AGG_EDGE(F0, e0);
            if (i1 < iend) AGG_EDGE(F1, e1);
            F0 = Fn0; e0 = en0; F1 = Fn1; e1 = en1;
            i0 = n0; i1 = n1;
        }
    } else {
        for (int e = srp[ni] + q; e < srp[ni + 1]; e += 8) {
            int s = csr[e];
            const char* r0 = P + ((size_t)s << 5);
            float4 F = *(const float4*)r0;
            float e8 = *(const float*)(r0 + 16);
            AGG_EDGE(F, e8);
        }
    }
#pragma unroll
    for (int m = 1; m <= 4; m <<= 1) {
        a0 += __shfl_xor(a0, m); a1 += __shfl_xor(a1, m);
        a2 += __shfl_xor(a2, m); a3 += __shfl_xor(a3, m);
        a4 += __shfl_xor(a4, m); a5 += __shfl_xor(a5, m);
        a6 += __shfl_xor(a6, m); a7 += __shfl_xor(a7, m);
        a8 += __shfl_xor(a8, m); den += __shfl_xor(den, m);
    }
    if (q == 0) {
        float* jp = jk + (size_t)l * Nn * Hh + (size_t)i * Hh;
        if (mode == 0) {
            // raw partial sums (no bias/relu/div)
            jp[0] = a0; jp[1] = a1; jp[2] = a2; jp[3] = a3; jp[4] = a4;
            jp[5] = a5; jp[6] = a6; jp[7] = a7; jp[8] = a8;
            denP[i] = den;
        } else {
            a0 += jp[0]; a1 += jp[1]; a2 += jp[2]; a3 += jp[3]; a4 += jp[4];
            a5 += jp[5]; a6 += jp[6]; a7 += jp[7]; a8 += jp[8];
            den += denP[i];
            float inv = 1.f / den;      // den >= 1 (self-loop in one half)
            jp[0] = fmaxf(a0*inv + biasl[0], 0.f);
            jp[1] = fmaxf(a1*inv + biasl[1], 0.f);
            jp[2] = fmaxf(a2*inv + biasl[2], 0.f);
            jp[3] = fmaxf(a3*inv + biasl[3], 0.f);
            jp[4] = fmaxf(a4*inv + biasl[4], 0.f);
            jp[5] = fmaxf(a5*inv + biasl[5], 0.f);
            jp[6] = fmaxf(a6*inv + biasl[6], 0.f);
            jp[7] = fmaxf(a7*inv + biasl[7], 0.f);
            jp[8] = fmaxf(a8*inv + biasl[8], 0.f);
        }
    }
}

// ============ pool + fc ============

__global__ __launch_bounds__(256) void k_graph_ptr(
    const int* __restrict__ batch, int* __restrict__ gp)
{
    int i = blockIdx.x * 256 + threadIdx.x;
    if (i >= Nn) return;
    int b = batch[i];
    if (i == 0) {
        for (int g = 0; g <= b; ++g) gp[g] = 0;
    } else {
        int pb = batch[i - 1];
        for (int g = pb + 1; g <= b; ++g) gp[g] = i;
    }
    if (i == Nn - 1) {
        for (int g = b + 1; g <= Gg; ++g) gp[g] = Nn;
    }
}

// Segmented max over layer-major jk [L][Nn][9]; concat order col = l*9+c.
__global__ __launch_bounds__(256) void k_pool_seg(
    const float* __restrict__ jk, const int* __restrict__ gp,
    float* __restrict__ pooled)
{
    int t = blockIdx.x * 256 + threadIdx.x;
    if (t >= Gg * JK) return;
    int g = t / JK, col = t - g * JK;
    int lc = col / Hh, cc = col - lc * Hh;
    const float* bp = jk + (size_t)lc * Nn * Hh + cc;
    int beg = gp[g], end = gp[g + 1];
    float m = 0.f;
    for (int i = beg; i < end; ++i)
        m = fmaxf(m, bp[(size_t)i * Hh]);
    pooled[t] = m;
}

__global__ __launch_bounds__(256) void k_fc(
    const float* __restrict__ pooled, const float* __restrict__ fcw,
    const float* __restrict__ fcb, float* __restrict__ out)
{
    int t = blockIdx.x * blockDim.x + threadIdx.x;
    if (t >= Gg * Cc) return;
    int g = t / Cc, c = t - g * Cc;
    float s = fcb[c];
    const float* pp = pooled + (size_t)g * JK;
#pragma unroll
    for (int j = 0; j < JK; ++j) s += pp[j] * fcw[j * Cc + c];
    out[t] = s;
}

extern "C" void kernel_launch(void* const* d_in, const int* in_sizes, int n_in,
                              void* d_out, int out_size, void* d_ws, size_t ws_size,
                              hipStream_t stream) {
    const float* x      = (const float*)d_in[0];   // [N,9]
    const int*   ei     = (const int*)d_in[1];     // [2,E]
    const int*   batch  = (const int*)d_in[2];     // [N] sorted
    const float* W      = (const float*)d_in[3];   // [L,9,9]
    const float* a_src  = (const float*)d_in[4];   // [L,9]
    const float* a_dst  = (const float*)d_in[5];   // [L,9]
    const float* bias   = (const float*)d_in[6];   // [L,9]
    const float* fc_w   = (const float*)d_in[7];   // [36,2]
    const float* fc_b   = (const float*)d_in[8];   // [2]
    float* out = (float*)d_out;

    // Workspace (~64.5 MB). histT aliases P, bucketed aliases jk — both dead
    // before P/jk are first written (same-stream ordering).
    char* P          = (char*)d_ws;                       // Nn*32B (6.4MB)
    float* jk        = (float*)(P + ((size_t)Nn << 5));   // Nn*JK (28.8MB)
    float* pooled    = jk + (size_t)Nn * JK;              // Gg*JK
    int* rpA         = (int*)(pooled + (size_t)Gg * JK);  // Nn+1
    int* rpB         = rpA + Nn + 1;                      // Nn+1
    int* gp          = rpB + Nn + 1;                      // Gg+1
    int* ctotH       = gp + Gg + 1;                       // 2*NCB
    int* cbaseH      = ctotH + 2 * NCB;                   // 2*NCB+1
    float* denP      = (float*)(cbaseH + 2 * NCB + 1);    // Nn (0.8MB)
    int* csr_src     = (int*)(denP + Nn);                 // EP (26.4MB)
    int* histT       = (int*)P;                           // aliases P
    unsigned* bucketed = (unsigned*)jk;                   // aliases jk

    const int* srcp = ei;
    const int* dstp = ei + Ee;

    // CSR build (edge structure is layer-invariant)
    hipMemsetAsync(ctotH, 0, 2 * NCB * sizeof(int), stream);
    kA_scatter<<<NBLKA, 256, 0, stream>>>(srcp, dstp, ctotH, histT, bucketed);
    k_scan    <<<1, 512, 0, stream>>>(ctotH, cbaseH, rpA, rpB);
    kB_csr    <<<NCB, 1024, 0, stream>>>(bucketed, histT, cbaseH, rpA, rpB,
                                         csr_src);

    for (int l = 0; l < Ll; ++l) {
        const float* xin = (l == 0) ? x : (jk + (size_t)(l - 1) * Nn * Hh);
        k_transform<<<NB, 256, 0, stream>>>(xin, Hh, W + l * Hh * Hh,
                                            a_dst + l * Hh, P);
        k_node_agg<<<NAB, 256, 0, stream>>>(rpA, csr_src, P, a_src + l * Hh,
                                            bias + l * Hh, jk, denP, l, 0);
        k_node_agg<<<NAB, 256, 0, stream>>>(rpB, csr_src, P, a_src + l * Hh,
                                            bias + l * Hh, jk, denP, l, 1);
    }
    k_graph_ptr<<<NB, 256, 0, stream>>>(batch, gp);
    k_pool_seg<<<(Gg * JK + 255) / 256, 256, 0, stream>>>(jk, gp, pooled);
    k_fc<<<(Gg * Cc + 255) / 256, 256, 0, stream>>>(pooled, fc_w, fc_b, out);
}